// Round 11
// baseline (299.867 us; speedup 1.0000x reference)
//
#include <hip/hip_runtime.h>
#include <math.h>

#define B_ 8
#define LP_ 64
#define LS_ 512
#define L_ 576
#define D_ 768
#define H_ 12
#define HD_ 64
#define V_ 50257
#define TOPK_ 10
#define CHUNKS_ 64
#define CHUNK_SZ_ 786  // ceil(V_/CHUNKS_); 64*786 = 50304 >= 50257

#define M_QKV 4608   // B_*L_
#define N_QKV 2304   // 3*D_
#define K_QKV 768

typedef __attribute__((ext_vector_type(8))) short bhalf8;
typedef __attribute__((ext_vector_type(4))) float floatx4;

#define GLOAD16(gptr, lptr)                                              \
  __builtin_amdgcn_global_load_lds(                                      \
      (const __attribute__((address_space(1))) unsigned int*)(gptr),     \
      (__attribute__((address_space(3))) unsigned int*)(lptr), 16, 0, 0)

// ---------------------------------------------------------------------------
// bf16 hi/lo split: x = hi + lo, hi = RNE-bf16(x), lo = RNE-bf16(x - hi).
// ---------------------------------------------------------------------------
__device__ inline void bf16split(float f, unsigned short& h, unsigned short& lo) {
  unsigned int u = __float_as_uint(f);
  unsigned short hb = (unsigned short)((u + 0x7FFFu + ((u >> 16) & 1u)) >> 16);
  float hf = __uint_as_float(((unsigned int)hb) << 16);
  float lf = f - hf;
  unsigned int ul = __float_as_uint(lf);
  unsigned short lb = (unsigned short)((ul + 0x7FFFu + ((ul >> 16) & 1u)) >> 16);
  h = hb; lo = lb;
}

// ---------------------------------------------------------------------------
// Kernel 0: build Ahi/Alo (x = concat(prompt,enc)) and Bhi/Blo (= Wqkv).
// ---------------------------------------------------------------------------
__global__ __launch_bounds__(256) void convert_split(
    const float* __restrict__ prompt, const float* __restrict__ enc,
    const float* __restrict__ Wqkv,
    unsigned short* __restrict__ Ahi, unsigned short* __restrict__ Alo,
    unsigned short* __restrict__ Bhi, unsigned short* __restrict__ Blo) {
  const int NA4 = M_QKV * K_QKV / 4;  // 884736
  const int NB4 = N_QKV * K_QKV / 4;  // 442368
  int i = blockIdx.x * 256 + threadIdx.x;
  if (i >= NA4 + NB4) return;
  const float* src;
  unsigned short *dh, *dl;
  int row, c4;
  if (i < NA4) {
    row = i / (K_QKV / 4);
    c4 = (i - row * (K_QKV / 4)) * 4;
    int b = row / L_, ll = row - (row / L_) * L_;
    src = (ll < LP_) ? (prompt + ((size_t)b * LP_ + ll) * D_ + c4)
                     : (enc + ((size_t)b * LS_ + (ll - LP_)) * D_ + c4);
    dh = Ahi + (size_t)row * K_QKV + c4;
    dl = Alo + (size_t)row * K_QKV + c4;
  } else {
    int j = i - NA4;
    row = j / (K_QKV / 4);
    c4 = (j - row * (K_QKV / 4)) * 4;
    src = Wqkv + (size_t)row * K_QKV + c4;
    dh = Bhi + (size_t)row * K_QKV + c4;
    dl = Blo + (size_t)row * K_QKV + c4;
  }
  float4 v = *(const float4*)src;
  ushort4 hv, lv;
  bf16split(v.x, hv.x, lv.x);
  bf16split(v.y, hv.y, lv.y);
  bf16split(v.z, hv.z, lv.z);
  bf16split(v.w, hv.w, lv.w);
  *(ushort4*)dh = hv;
  *(ushort4*)dl = lv;
}

// ---------------------------------------------------------------------------
// Kernel 1: QKV projection, split-bf16 MFMA, fused single K-pass.
// Tile 64(M)x128(N), BK=32 -> grid 1296 (5 blocks/CU vs 648/2.5: the
// round-10 counters showed latency-bound at Occupancy 14% — TLP is the
// binding constraint, per m102's shape curve). 4 waves, each 64x32 output.
// LDS 24 KB single buffer; same verified BK=32 XOR swizzle.
// ---------------------------------------------------------------------------
__global__ __launch_bounds__(256) void qkv_mfma(
    const unsigned short* __restrict__ Ahi, const unsigned short* __restrict__ Alo,
    const unsigned short* __restrict__ Bhi, const unsigned short* __restrict__ Blo,
    unsigned short* __restrict__ Qhi, unsigned short* __restrict__ Qlo,
    unsigned short* __restrict__ Khi, unsigned short* __restrict__ Klo,
    float* __restrict__ Vv) {
  __shared__ unsigned short Ath[64 * 32];   // 4 KB each A buffer
  __shared__ unsigned short Atl[64 * 32];
  __shared__ unsigned short Bth[128 * 32];  // 8 KB each B buffer
  __shared__ unsigned short Btl[128 * 32];  // total 24 KB
  const int flat = blockIdx.x;
  const int swz = (flat & 7) * 162 + (flat >> 3);  // 1296 = 8 XCD x 162
  const int bx = swz % 18, by = swz / 18;          // bx<18 (N), by<72 (M)
  const int n0 = bx * 128, m0 = by * 64;
  const int tid = threadIdx.x;
  const int l = tid & 63;
  const int w = tid >> 6;          // wave 0..3, owns N-cols w*32..+32

  floatx4 acc[4][2];
#pragma unroll
  for (int i = 0; i < 4; ++i)
#pragma unroll
    for (int j = 0; j < 2; ++j) acc[i][j] = (floatx4){0.f, 0.f, 0.f, 0.f};

  const int r4 = l >> 2;                     // row within 16-row group
  const int cs = (l & 3) ^ ((l >> 3) & 3);   // pre-swizzled source chunk
  const int lm = l & 15;                     // fragment row/col within 16
  const int lk = l >> 4;                     // fragment k-group 0..3
  const int cb = lk ^ ((lm >> 1) & 3);       // stored chunk for frag reads

  for (int kt = 0; kt < 24; ++kt) {
    const int kk0 = kt * 32;
    __syncthreads();
    {  // A: 64 rows, one 16-row gload16 pair per wave
      const int row = w * 16;
      const size_t ga = (size_t)(m0 + row + r4) * K_QKV + kk0 + cs * 8;
      GLOAD16(Ahi + ga, &Ath[row * 32]);
      GLOAD16(Alo + ga, &Atl[row * 32]);
    }
#pragma unroll
    for (int i = 0; i < 2; ++i) {  // B: 128 rows, two 16-row groups per wave
      const int row = w * 32 + i * 16;
      const size_t gb = (size_t)(n0 + row + r4) * K_QKV + kk0 + cs * 8;
      GLOAD16(Bhi + gb, &Bth[row * 32]);
      GLOAD16(Blo + gb, &Btl[row * 32]);
    }
    __syncthreads();

    bhalf8 ah[4], al[4], bh8[2], bl8[2];
#pragma unroll
    for (int f = 0; f < 4; ++f) {
      const int ma = f * 16 + lm;
      const int oa = ma * 32 + cb * 8;
      ah[f] = *(const bhalf8*)&Ath[oa];
      al[f] = *(const bhalf8*)&Atl[oa];
    }
#pragma unroll
    for (int f = 0; f < 2; ++f) {
      const int nb = w * 32 + f * 16 + lm;
      const int ob = nb * 32 + cb * 8;
      bh8[f] = *(const bhalf8*)&Bth[ob];
      bl8[f] = *(const bhalf8*)&Btl[ob];
    }
#pragma unroll
    for (int fm = 0; fm < 4; ++fm)
#pragma unroll
      for (int fn = 0; fn < 2; ++fn) {
        acc[fm][fn] = __builtin_amdgcn_mfma_f32_16x16x32_bf16(
            ah[fm], bh8[fn], acc[fm][fn], 0, 0, 0);
        acc[fm][fn] = __builtin_amdgcn_mfma_f32_16x16x32_bf16(
            al[fm], bh8[fn], acc[fm][fn], 0, 0, 0);
        acc[fm][fn] = __builtin_amdgcn_mfma_f32_16x16x32_bf16(
            ah[fm], bl8[fn], acc[fm][fn], 0, 0, 0);
      }
  }

  // C write: row m = lk*4 + j, col n = lm within each 16x16 fragment.
#pragma unroll
  for (int fm = 0; fm < 4; ++fm) {
#pragma unroll
    for (int fn = 0; fn < 2; ++fn) {
#pragma unroll
      for (int j = 0; j < 4; ++j) {
        int m = m0 + fm * 16 + lk * 4 + j;
        int n = n0 + w * 32 + fn * 16 + lm;
        int b = m / L_;
        int ll = m - b * L_;
        int part = n / D_;
        int rem = n - part * D_;
        int h = rem >> 6, e = rem & 63;
        size_t idx = (((size_t)b * H_ + h) * L_ + ll) * HD_ + e;
        float val = acc[fm][fn][j];
        if (part == 2) {
          Vv[idx] = val;
        } else {
          unsigned short hv, lv;
          bf16split(val, hv, lv);
          if (part == 0) { Qhi[idx] = hv; Qlo[idx] = lv; }
          else           { Khi[idx] = hv; Klo[idx] = lv; }
        }
      }
    }
  }
}

// ---------------------------------------------------------------------------
// Kernel 2: attention column sums via split-bf16 MFMA (round-6 single-buffer).
// ---------------------------------------------------------------------------
__global__ __launch_bounds__(256, 2) void attn_mfma(
    const unsigned short* __restrict__ Qhi, const unsigned short* __restrict__ Qlo,
    const unsigned short* __restrict__ Khi, const unsigned short* __restrict__ Klo,
    float* __restrict__ c) {
  __shared__ unsigned short Qh[64 * 64], Ql[64 * 64];  // 8 KB each
  __shared__ unsigned short Kh[64 * 64], Kl[64 * 64];
  __shared__ float c_lds[L_];
  const int qt = blockIdx.x;   // 0..8
  const int bh = blockIdx.y;   // 0..95
  const int tid = threadIdx.x;
  const int w = tid >> 6, l = tid & 63;
  const int lm = l & 15, lk = l >> 4;
  const int r8 = l >> 3;
  const int cs = (l & 7) ^ r8;

  for (int i = tid; i < L_; i += 256) c_lds[i] = 0.f;

  {
    const size_t gbase = ((size_t)bh * L_ + qt * 64) * HD_;
#pragma unroll
    for (int i = 0; i < 2; ++i) {
      int row = w * 16 + i * 8;
      GLOAD16(Qhi + gbase + (size_t)(row + r8) * HD_ + cs * 8, &Qh[row * 64]);
      GLOAD16(Qlo + gbase + (size_t)(row + r8) * HD_ + cs * 8, &Ql[row * 64]);
    }
  }

  floatx4 p[9][4];
#pragma unroll
  for (int kt = 0; kt < 9; ++kt)
#pragma unroll
    for (int fn = 0; fn < 4; ++fn) p[kt][fn] = (floatx4){0.f, 0.f, 0.f, 0.f};
  float zpart[4] = {0.f, 0.f, 0.f, 0.f};

#pragma unroll
  for (int kt = 0; kt < 9; ++kt) {
    __syncthreads();
    const size_t kb = ((size_t)bh * L_ + kt * 64) * HD_;
#pragma unroll
    for (int i = 0; i < 2; ++i) {
      int row = w * 16 + i * 8;
      GLOAD16(Khi + kb + (size_t)(row + r8) * HD_ + cs * 8, &Kh[row * 64]);
      GLOAD16(Klo + kb + (size_t)(row + r8) * HD_ + cs * 8, &Kl[row * 64]);
    }
    __syncthreads();
#pragma unroll
    for (int s = 0; s < 2; ++s) {
      const int ma = w * 16 + lm;
      const int ca = (s * 4 + lk) ^ (ma & 7);
      bhalf8 ah = *(const bhalf8*)&Qh[ma * 64 + ca * 8];
      bhalf8 al = *(const bhalf8*)&Ql[ma * 64 + ca * 8];
#pragma unroll
      for (int fn = 0; fn < 4; ++fn) {
        const int nb = fn * 16 + lm;
        const int cb2 = (s * 4 + lk) ^ (nb & 7);
        bhalf8 bh8 = *(const bhalf8*)&Kh[nb * 64 + cb2 * 8];
        bhalf8 bl8 = *(const bhalf8*)&Kl[nb * 64 + cb2 * 8];
        p[kt][fn] = __builtin_amdgcn_mfma_f32_16x16x32_bf16(ah, bh8, p[kt][fn], 0, 0, 0);
        p[kt][fn] = __builtin_amdgcn_mfma_f32_16x16x32_bf16(al, bh8, p[kt][fn], 0, 0, 0);
        p[kt][fn] = __builtin_amdgcn_mfma_f32_16x16x32_bf16(ah, bl8, p[kt][fn], 0, 0, 0);
      }
    }
#pragma unroll
    for (int fn = 0; fn < 4; ++fn)
#pragma unroll
      for (int j = 0; j < 4; ++j) {
        float e = __expf(p[kt][fn][j] * 0.125f);
        p[kt][fn][j] = e;
        zpart[j] += e;
      }
  }

  float invz[4];
#pragma unroll
  for (int j = 0; j < 4; ++j) {
    float z = zpart[j];
    z += __shfl_xor(z, 1);
    z += __shfl_xor(z, 2);
    z += __shfl_xor(z, 4);
    z += __shfl_xor(z, 8);
    invz[j] = 1.f / z;
  }

#pragma unroll
  for (int kt = 0; kt < 9; ++kt)
#pragma unroll
    for (int fn = 0; fn < 4; ++fn) {
      float cp = p[kt][fn][0] * invz[0] + p[kt][fn][1] * invz[1] +
                 p[kt][fn][2] * invz[2] + p[kt][fn][3] * invz[3];
      cp += __shfl_xor(cp, 16);
      cp += __shfl_xor(cp, 32);
      if (lk == 0) atomicAdd(&c_lds[kt * 64 + fn * 16 + lm], cp);
    }
  __syncthreads();
  for (int i = tid; i < L_; i += 256)
    atomicAdd(&c[(size_t)bh * L_ + i], c_lds[i]);
}

// ---------------------------------------------------------------------------
// Kernel 3: t[b, h*64+e] = sum_k c[b,h,k] * V[b,h,k,e]
// ---------------------------------------------------------------------------
__global__ void cv_kernel(const float* __restrict__ c,
                          const float* __restrict__ Vv,
                          float* __restrict__ t) {
  const int bh = blockIdx.x;
  const int e = threadIdx.x;
  const float* cb = c + (size_t)bh * L_;
  const float* Vb = Vv + (size_t)bh * L_ * HD_;
  float acc = 0.f;
  for (int k = 0; k < L_; ++k) acc = fmaf(cb[k], Vb[(size_t)k * HD_ + e], acc);
  int b = bh / H_, h = bh - (bh / H_) * H_;
  t[(size_t)b * D_ + h * HD_ + e] = acc;
}

// ---------------------------------------------------------------------------
// Kernel 4: s[b,d] = sum_d' t[b,d'] * Wproj[d,d'] + L*bproj[d]
// ---------------------------------------------------------------------------
__global__ __launch_bounds__(768) void proj_kernel(
    const float* __restrict__ t, const float* __restrict__ Wp,
    const float* __restrict__ bp, float* __restrict__ s) {
  __shared__ float tl[768];
  const int b = blockIdx.x, d = threadIdx.x;
  tl[d] = t[(size_t)b * D_ + d];
  __syncthreads();
  float acc = (float)L_ * bp[d];
  const float* wrow = Wp + (size_t)d * D_;
  for (int dp = 0; dp < D_; ++dp) acc = fmaf(tl[dp], wrow[dp], acc);
  s[(size_t)b * D_ + d] = acc;
}

// ---------------------------------------------------------------------------
// Kernel 5: sim[b,v] = sum_d s[b,d] * word_emd[v,d]. Streaming (round-10
// version, measured best).
// ---------------------------------------------------------------------------
__global__ __launch_bounds__(256) void sim_kernel(
    const float* __restrict__ s, const float* __restrict__ w,
    float* __restrict__ sim) {
  __shared__ float s2[192 * 36];  // 27.6 KB
  const int tid = threadIdx.x;
  for (int e = tid; e < 6144; e += 256) {
    int b = e / 768;
    int d = e - b * 768;
    int k = d >> 6, pj = d & 63;
    int p = pj >> 2, j = pj & 3;
    s2[(k * 16 + p) * 36 + j * 8 + b] = s[e];
  }
  __syncthreads();

  const int wv = tid >> 6, l = tid & 63;
  const int g = l >> 4, p = l & 15;
  const int base = blockIdx.x * 32 + wv * 8;
  const int rA = base + g, rB = base + g + 4;
  const int cA = (rA < V_) ? rA : (V_ - 1);
  const int cB = (rB < V_) ? rB : (V_ - 1);
  const float* wpA = w + (size_t)cA * D_ + p * 4;
  const float* wpB = w + (size_t)cB * D_ + p * 4;

  float accA[8] = {}, accB[8] = {};
  float4 wa0 = *(const float4*)(wpA);
  float4 wb0 = *(const float4*)(wpB);
  float4 wa1 = *(const float4*)(wpA + 64);
  float4 wb1 = *(const float4*)(wpB + 64);

#pragma unroll
  for (int k = 0; k < 12; ++k) {
    float4 cwa = (k & 1) ? wa1 : wa0;
    float4 cwb = (k & 1) ? wb1 : wb0;
    if (k + 2 < 12) {
      if (k & 1) {
        wa1 = *(const float4*)(wpA + (k + 2) * 64);
        wb1 = *(const float4*)(wpB + (k + 2) * 64);
      } else {
        wa0 = *(const float4*)(wpA + (k + 2) * 64);
        wb0 = *(const float4*)(wpB + (k + 2) * 64);
      }
    }
    const float* sb = &s2[(k * 16 + p) * 36];
    float4 sj[8];
#pragma unroll
    for (int jj = 0; jj < 8; ++jj) sj[jj] = *(const float4*)(sb + jj * 4);
    float ca[4] = {cwa.x, cwa.y, cwa.z, cwa.w};
    float cb[4] = {cwb.x, cwb.y, cwb.z, cwb.w};
#pragma unroll
    for (int j = 0; j < 4; ++j) {
      accA[0] = fmaf(ca[j], sj[2 * j].x, accA[0]);
      accA[1] = fmaf(ca[j], sj[2 * j].y, accA[1]);
      accA[2] = fmaf(ca[j], sj[2 * j].z, accA[2]);
      accA[3] = fmaf(ca[j], sj[2 * j].w, accA[3]);
      accA[4] = fmaf(ca[j], sj[2 * j + 1].x, accA[4]);
      accA[5] = fmaf(ca[j], sj[2 * j + 1].y, accA[5]);
      accA[6] = fmaf(ca[j], sj[2 * j + 1].z, accA[6]);
      accA[7] = fmaf(ca[j], sj[2 * j + 1].w, accA[7]);
      accB[0] = fmaf(cb[j], sj[2 * j].x, accB[0]);
      accB[1] = fmaf(cb[j], sj[2 * j].y, accB[1]);
      accB[2] = fmaf(cb[j], sj[2 * j].z, accB[2]);
      accB[3] = fmaf(cb[j], sj[2 * j].w, accB[3]);
      accB[4] = fmaf(cb[j], sj[2 * j + 1].x, accB[4]);
      accB[5] = fmaf(cb[j], sj[2 * j + 1].y, accB[5]);
      accB[6] = fmaf(cb[j], sj[2 * j + 1].z, accB[6]);
      accB[7] = fmaf(cb[j], sj[2 * j + 1].w, accB[7]);
    }
  }

#pragma unroll
  for (int off = 1; off < 16; off <<= 1) {
#pragma unroll
    for (int b = 0; b < 8; ++b) {
      accA[b] += __shfl_xor(accA[b], off);
      accB[b] += __shfl_xor(accB[b], off);
    }
  }
  if (p == 0) {
#pragma unroll
    for (int b = 0; b < 8; ++b) {
      if (rA < V_) sim[(size_t)b * V_ + rA] = accA[b];
      if (rB < V_) sim[(size_t)b * V_ + rB] = accB[b];
    }
  }
}

// ---------------------------------------------------------------------------
// Kernel 6a: per-chunk local top-10.
// ---------------------------------------------------------------------------
__global__ __launch_bounds__(256) void topk_stage1(
    const float* __restrict__ sim, float* __restrict__ cv,
    int* __restrict__ ci) {
  __shared__ float vals[CHUNK_SZ_];
  __shared__ float bv[256];
  __shared__ int bi[256];
  const int chunk = blockIdx.x, b = blockIdx.y, tid = threadIdx.x;
  const int base = chunk * CHUNK_SZ_;
  const float* row = sim + (size_t)b * V_;
  for (int i = tid; i < CHUNK_SZ_; i += 256) {
    int v = base + i;
    vals[i] = (v < V_) ? row[v] : -INFINITY;
  }
  __syncthreads();
  for (int k = 0; k < TOPK_; ++k) {
    float best = -INFINITY;
    int besti = CHUNK_SZ_;
    for (int i = tid; i < CHUNK_SZ_; i += 256) {
      float x = vals[i];
      if (x > best) { best = x; besti = i; }
    }
    bv[tid] = best; bi[tid] = besti;
    __syncthreads();
    for (int off = 128; off > 0; off >>= 1) {
      if (tid < off) {
        float ov = bv[tid + off]; int oi = bi[tid + off];
        if (ov > bv[tid] || (ov == bv[tid] && oi < bi[tid])) {
          bv[tid] = ov; bi[tid] = oi;
        }
      }
      __syncthreads();
    }
    if (tid == 0) {
      int slot = (b * CHUNKS_ + chunk) * TOPK_ + k;
      cv[slot] = bv[0];
      ci[slot] = base + bi[0];
      if (bi[0] < CHUNK_SZ_) vals[bi[0]] = -INFINITY;
    }
    __syncthreads();
  }
}

// ---------------------------------------------------------------------------
// Kernel 6b: reduce 64 chunks x 10 candidates -> global top-10 per batch.
// ---------------------------------------------------------------------------
__global__ __launch_bounds__(256) void topk_stage2(
    const float* __restrict__ cv, const int* __restrict__ ci,
    int* __restrict__ topk) {
  const int NC = CHUNKS_ * TOPK_;  // 640
  __shared__ float vals[CHUNKS_ * TOPK_];
  __shared__ int gidx[CHUNKS_ * TOPK_];
  __shared__ float bv[256];
  __shared__ int bi[256];
  const int b = blockIdx.x, tid = threadIdx.x;
  for (int i = tid; i < NC; i += 256) {
    vals[i] = cv[(size_t)b * NC + i];
    gidx[i] = ci[(size_t)b * NC + i];
  }
  __syncthreads();
  for (int k = 0; k < TOPK_; ++k) {
    float best = -INFINITY;
    int bslot = NC;
    for (int i = tid; i < NC; i += 256) {
      float x = vals[i];
      if (x > best) { best = x; bslot = i; }
    }
    bv[tid] = best; bi[tid] = bslot;
    __syncthreads();
    for (int off = 128; off > 0; off >>= 1) {
      if (tid < off) {
        float ov = bv[tid + off]; int oi = bi[tid + off];
        if (ov > bv[tid] || (ov == bv[tid] && oi < bi[tid])) {
          bv[tid] = ov; bi[tid] = oi;
        }
      }
      __syncthreads();
    }
    if (tid == 0) {
      int slot = bi[0];
      topk[b * TOPK_ + k] = (slot < NC) ? gidx[slot] : 0;
      if (slot < NC) vals[slot] = -INFINITY;
    }
    __syncthreads();
  }
}

// ---------------------------------------------------------------------------
// Kernel 7: gather word_emd rows -> output [B, K, D]
// ---------------------------------------------------------------------------
__global__ void gather_kernel(const int* __restrict__ topk,
                              const float* __restrict__ w,
                              float* __restrict__ out) {
  const int bk = blockIdx.x;
  const int idx = topk[bk];
  const int t4 = threadIdx.x << 2;
  *(float4*)(out + (size_t)bk * D_ + t4) =
      *(const float4*)(w + (size_t)idx * D_ + t4);
}

extern "C" void kernel_launch(void* const* d_in, const int* in_sizes, int n_in,
                              void* d_out, int out_size, void* d_ws,
                              size_t ws_size, hipStream_t stream) {
  const float* prompt = (const float*)d_in[0];
  const float* enc    = (const float*)d_in[1];
  const float* wemd   = (const float*)d_in[2];
  const float* Wqkv   = (const float*)d_in[3];
  const float* Wproj  = (const float*)d_in[4];
  const float* bproj  = (const float*)d_in[5];
  float* out = (float*)d_out;

  float* ws = (float*)d_ws;
  const size_t QSZ = (size_t)B_ * H_ * L_ * HD_;  // 3,538,944
  float* Vv   = ws;                        // fp32 V
  float* c    = Vv + QSZ;                  // 96*576 = 55,296
  float* t    = c + (size_t)B_ * H_ * L_;  // 6144
  float* s    = t + (size_t)B_ * D_;       // 6144
  float* sim  = s + (size_t)B_ * D_;       // 8*50257 = 402,056
  float* cand_v = sim + (size_t)B_ * V_;   // 8*640 = 5120
  int* cand_i   = (int*)(cand_v + (size_t)B_ * CHUNKS_ * TOPK_);
  int* topk     = cand_i + (size_t)B_ * CHUNKS_ * TOPK_;
  unsigned short* Qhi = (unsigned short*)(topk + B_ * TOPK_ + 64);
  unsigned short* Qlo = Qhi + QSZ;
  unsigned short* Khi = Qlo + QSZ;
  unsigned short* Klo = Khi + QSZ;
  unsigned short* Ahi = Klo + QSZ;
  unsigned short* Alo = Ahi + (size_t)M_QKV * K_QKV;
  unsigned short* Bhi = Alo + (size_t)M_QKV * K_QKV;
  unsigned short* Blo = Bhi + (size_t)N_QKV * K_QKV;

  hipMemsetAsync(c, 0, (size_t)B_ * H_ * L_ * sizeof(float), stream);

  const int NCONV = (M_QKV * K_QKV + N_QKV * K_QKV) / 4;  // 1,327,104
  convert_split<<<(NCONV + 255) / 256, 256, 0, stream>>>(
      prompt, enc, Wqkv, Ahi, Alo, Bhi, Blo);
  qkv_mfma<<<(M_QKV / 64) * (N_QKV / 128), 256, 0, stream>>>(
      Ahi, Alo, Bhi, Blo, Qhi, Qlo, Khi, Klo, Vv);
  attn_mfma<<<dim3(9, 96), 256, 0, stream>>>(Qhi, Qlo, Khi, Klo, c);
  cv_kernel<<<96, 64, 0, stream>>>(c, Vv, t);
  proj_kernel<<<8, 768, 0, stream>>>(t, Wproj, bproj, s);
  sim_kernel<<<(V_ + 31) / 32, 256, 0, stream>>>(s, wemd, sim);
  topk_stage1<<<dim3(CHUNKS_, B_), 256, 0, stream>>>(sim, cand_v, cand_i);
  topk_stage2<<<B_, 256, 0, stream>>>(cand_v, cand_i, topk);
  gather_kernel<<<80, 192, 0, stream>>>(topk, wemd, out);
}

// Round 12
// 270.777 us; speedup vs baseline: 1.1074x; 1.1074x over previous
//
#include <hip/hip_runtime.h>
#include <math.h>

#define B_ 8
#define LP_ 64
#define LS_ 512
#define L_ 576
#define D_ 768
#define H_ 12
#define HD_ 64
#define V_ 50257
#define TOPK_ 10
#define CHUNKS_ 64
#define CHUNK_SZ_ 786  // ceil(V_/CHUNKS_); 64*786 = 50304 >= 50257

#define M_QKV 4608   // B_*L_
#define N_QKV 2304   // 3*D_
#define K_QKV 768

typedef __attribute__((ext_vector_type(8))) short bhalf8;
typedef __attribute__((ext_vector_type(4))) float floatx4;

#define GLOAD16(gptr, lptr)                                              \
  __builtin_amdgcn_global_load_lds(                                      \
      (const __attribute__((address_space(1))) unsigned int*)(gptr),     \
      (__attribute__((address_space(3))) unsigned int*)(lptr), 16, 0, 0)

// ---------------------------------------------------------------------------
// bf16 hi/lo split: x = hi + lo, hi = RNE-bf16(x), lo = RNE-bf16(x - hi).
// ---------------------------------------------------------------------------
__device__ inline void bf16split(float f, unsigned short& h, unsigned short& lo) {
  unsigned int u = __float_as_uint(f);
  unsigned short hb = (unsigned short)((u + 0x7FFFu + ((u >> 16) & 1u)) >> 16);
  float hf = __uint_as_float(((unsigned int)hb) << 16);
  float lf = f - hf;
  unsigned int ul = __float_as_uint(lf);
  unsigned short lb = (unsigned short)((ul + 0x7FFFu + ((ul >> 16) & 1u)) >> 16);
  h = hb; lo = lb;
}

// ---------------------------------------------------------------------------
// Kernel 0: build Ahi/Alo (x = concat(prompt,enc)) and Bhi/Blo (= Wqkv).
// ---------------------------------------------------------------------------
__global__ __launch_bounds__(256) void convert_split(
    const float* __restrict__ prompt, const float* __restrict__ enc,
    const float* __restrict__ Wqkv,
    unsigned short* __restrict__ Ahi, unsigned short* __restrict__ Alo,
    unsigned short* __restrict__ Bhi, unsigned short* __restrict__ Blo) {
  const int NA4 = M_QKV * K_QKV / 4;  // 884736
  const int NB4 = N_QKV * K_QKV / 4;  // 442368
  int i = blockIdx.x * 256 + threadIdx.x;
  if (i >= NA4 + NB4) return;
  const float* src;
  unsigned short *dh, *dl;
  int row, c4;
  if (i < NA4) {
    row = i / (K_QKV / 4);
    c4 = (i - row * (K_QKV / 4)) * 4;
    int b = row / L_, ll = row - (row / L_) * L_;
    src = (ll < LP_) ? (prompt + ((size_t)b * LP_ + ll) * D_ + c4)
                     : (enc + ((size_t)b * LS_ + (ll - LP_)) * D_ + c4);
    dh = Ahi + (size_t)row * K_QKV + c4;
    dl = Alo + (size_t)row * K_QKV + c4;
  } else {
    int j = i - NA4;
    row = j / (K_QKV / 4);
    c4 = (j - row * (K_QKV / 4)) * 4;
    src = Wqkv + (size_t)row * K_QKV + c4;
    dh = Bhi + (size_t)row * K_QKV + c4;
    dl = Blo + (size_t)row * K_QKV + c4;
  }
  float4 v = *(const float4*)src;
  ushort4 hv, lv;
  bf16split(v.x, hv.x, lv.x);
  bf16split(v.y, hv.y, lv.y);
  bf16split(v.z, hv.z, lv.z);
  bf16split(v.w, hv.w, lv.w);
  *(ushort4*)dh = hv;
  *(ushort4*)dl = lv;
}

// ---------------------------------------------------------------------------
// Kernel 1: QKV projection, split-bf16 MFMA, fused single K-pass.
// Tile 64(M)x128(N), BK=64 -> 12 K-steps (half the barrier/drain count of
// all prior ~110us variants; r6/r11 invariance isolated drain-count as the
// binding cost). LDS 48 KB single buffer (3 blocks/CU). Staging/read
// swizzle = the verified rounds-3-5 BK=64 pair (bank-conflict 0 measured).
// ---------------------------------------------------------------------------
__global__ __launch_bounds__(256) void qkv_mfma(
    const unsigned short* __restrict__ Ahi, const unsigned short* __restrict__ Alo,
    const unsigned short* __restrict__ Bhi, const unsigned short* __restrict__ Blo,
    unsigned short* __restrict__ Qhi, unsigned short* __restrict__ Qlo,
    unsigned short* __restrict__ Khi, unsigned short* __restrict__ Klo,
    float* __restrict__ Vv) {
  __shared__ unsigned short Ath[64 * 64];    // 8 KB each A buffer
  __shared__ unsigned short Atl[64 * 64];
  __shared__ unsigned short Bth[128 * 64];   // 16 KB each B buffer
  __shared__ unsigned short Btl[128 * 64];   // total 48 KB
  const int flat = blockIdx.x;
  const int swz = (flat & 7) * 162 + (flat >> 3);  // 1296 = 8 XCD x 162
  const int bx = swz % 18, by = swz / 18;          // bx<18 (N), by<72 (M)
  const int n0 = bx * 128, m0 = by * 64;
  const int tid = threadIdx.x;
  const int l = tid & 63;
  const int w = tid >> 6;          // wave 0..3, owns N-cols w*32..+32

  floatx4 acc[4][2];
#pragma unroll
  for (int i = 0; i < 4; ++i)
#pragma unroll
    for (int j = 0; j < 2; ++j) acc[i][j] = (floatx4){0.f, 0.f, 0.f, 0.f};

  const int r8 = l >> 3;                 // row within 8-row gload group
  const int cs = (l & 7) ^ r8;           // pre-swizzled source 16B chunk
  const int lm = l & 15;                 // fragment row/col within 16
  const int lk = l >> 4;                 // fragment k-group 0..3

  for (int kt = 0; kt < 12; ++kt) {
    const int kk0 = kt * 64;
    __syncthreads();
#pragma unroll
    for (int i = 0; i < 2; ++i) {  // A: 64 rows, 8 groups, 2 per wave
      const int row = w * 16 + i * 8;
      const size_t ga = (size_t)(m0 + row + r8) * K_QKV + kk0 + cs * 8;
      GLOAD16(Ahi + ga, &Ath[row * 64]);
      GLOAD16(Alo + ga, &Atl[row * 64]);
    }
#pragma unroll
    for (int i = 0; i < 4; ++i) {  // B: 128 rows, 16 groups, 4 per wave
      const int row = w * 32 + i * 8;
      const size_t gb = (size_t)(n0 + row + r8) * K_QKV + kk0 + cs * 8;
      GLOAD16(Bhi + gb, &Bth[row * 64]);
      GLOAD16(Blo + gb, &Btl[row * 64]);
    }
    __syncthreads();

#pragma unroll
    for (int s = 0; s < 2; ++s) {
      bhalf8 ah[4], al[4], bh8[2], bl8[2];
#pragma unroll
      for (int f = 0; f < 4; ++f) {
        const int ma = f * 16 + lm;
        const int ca = (s * 4 + lk) ^ (ma & 7);
        ah[f] = *(const bhalf8*)&Ath[ma * 64 + ca * 8];
        al[f] = *(const bhalf8*)&Atl[ma * 64 + ca * 8];
      }
#pragma unroll
      for (int f = 0; f < 2; ++f) {
        const int nb = w * 32 + f * 16 + lm;
        const int cb2 = (s * 4 + lk) ^ (nb & 7);
        bh8[f] = *(const bhalf8*)&Bth[nb * 64 + cb2 * 8];
        bl8[f] = *(const bhalf8*)&Btl[nb * 64 + cb2 * 8];
      }
#pragma unroll
      for (int fm = 0; fm < 4; ++fm)
#pragma unroll
        for (int fn = 0; fn < 2; ++fn) {
          acc[fm][fn] = __builtin_amdgcn_mfma_f32_16x16x32_bf16(
              ah[fm], bh8[fn], acc[fm][fn], 0, 0, 0);
          acc[fm][fn] = __builtin_amdgcn_mfma_f32_16x16x32_bf16(
              al[fm], bh8[fn], acc[fm][fn], 0, 0, 0);
          acc[fm][fn] = __builtin_amdgcn_mfma_f32_16x16x32_bf16(
              ah[fm], bl8[fn], acc[fm][fn], 0, 0, 0);
        }
    }
  }

  // C write: row m = lk*4 + j, col n = lm within each 16x16 fragment.
#pragma unroll
  for (int fm = 0; fm < 4; ++fm) {
#pragma unroll
    for (int fn = 0; fn < 2; ++fn) {
#pragma unroll
      for (int j = 0; j < 4; ++j) {
        int m = m0 + fm * 16 + lk * 4 + j;
        int n = n0 + w * 32 + fn * 16 + lm;
        int b = m / L_;
        int ll = m - b * L_;
        int part = n / D_;
        int rem = n - part * D_;
        int h = rem >> 6, e = rem & 63;
        size_t idx = (((size_t)b * H_ + h) * L_ + ll) * HD_ + e;
        float val = acc[fm][fn][j];
        if (part == 2) {
          Vv[idx] = val;
        } else {
          unsigned short hv, lv;
          bf16split(val, hv, lv);
          if (part == 0) { Qhi[idx] = hv; Qlo[idx] = lv; }
          else           { Khi[idx] = hv; Klo[idx] = lv; }
        }
      }
    }
  }
}

// ---------------------------------------------------------------------------
// Kernel 2: attention column sums via split-bf16 MFMA (round-6 single-buffer).
// ---------------------------------------------------------------------------
__global__ __launch_bounds__(256, 2) void attn_mfma(
    const unsigned short* __restrict__ Qhi, const unsigned short* __restrict__ Qlo,
    const unsigned short* __restrict__ Khi, const unsigned short* __restrict__ Klo,
    float* __restrict__ c) {
  __shared__ unsigned short Qh[64 * 64], Ql[64 * 64];  // 8 KB each
  __shared__ unsigned short Kh[64 * 64], Kl[64 * 64];
  __shared__ float c_lds[L_];
  const int qt = blockIdx.x;   // 0..8
  const int bh = blockIdx.y;   // 0..95
  const int tid = threadIdx.x;
  const int w = tid >> 6, l = tid & 63;
  const int lm = l & 15, lk = l >> 4;
  const int r8 = l >> 3;
  const int cs = (l & 7) ^ r8;

  for (int i = tid; i < L_; i += 256) c_lds[i] = 0.f;

  {
    const size_t gbase = ((size_t)bh * L_ + qt * 64) * HD_;
#pragma unroll
    for (int i = 0; i < 2; ++i) {
      int row = w * 16 + i * 8;
      GLOAD16(Qhi + gbase + (size_t)(row + r8) * HD_ + cs * 8, &Qh[row * 64]);
      GLOAD16(Qlo + gbase + (size_t)(row + r8) * HD_ + cs * 8, &Ql[row * 64]);
    }
  }

  floatx4 p[9][4];
#pragma unroll
  for (int kt = 0; kt < 9; ++kt)
#pragma unroll
    for (int fn = 0; fn < 4; ++fn) p[kt][fn] = (floatx4){0.f, 0.f, 0.f, 0.f};
  float zpart[4] = {0.f, 0.f, 0.f, 0.f};

#pragma unroll
  for (int kt = 0; kt < 9; ++kt) {
    __syncthreads();
    const size_t kb = ((size_t)bh * L_ + kt * 64) * HD_;
#pragma unroll
    for (int i = 0; i < 2; ++i) {
      int row = w * 16 + i * 8;
      GLOAD16(Khi + kb + (size_t)(row + r8) * HD_ + cs * 8, &Kh[row * 64]);
      GLOAD16(Klo + kb + (size_t)(row + r8) * HD_ + cs * 8, &Kl[row * 64]);
    }
    __syncthreads();
#pragma unroll
    for (int s = 0; s < 2; ++s) {
      const int ma = w * 16 + lm;
      const int ca = (s * 4 + lk) ^ (ma & 7);
      bhalf8 ah = *(const bhalf8*)&Qh[ma * 64 + ca * 8];
      bhalf8 al = *(const bhalf8*)&Ql[ma * 64 + ca * 8];
#pragma unroll
      for (int fn = 0; fn < 4; ++fn) {
        const int nb = fn * 16 + lm;
        const int cb2 = (s * 4 + lk) ^ (nb & 7);
        bhalf8 bh8 = *(const bhalf8*)&Kh[nb * 64 + cb2 * 8];
        bhalf8 bl8 = *(const bhalf8*)&Kl[nb * 64 + cb2 * 8];
        p[kt][fn] = __builtin_amdgcn_mfma_f32_16x16x32_bf16(ah, bh8, p[kt][fn], 0, 0, 0);
        p[kt][fn] = __builtin_amdgcn_mfma_f32_16x16x32_bf16(al, bh8, p[kt][fn], 0, 0, 0);
        p[kt][fn] = __builtin_amdgcn_mfma_f32_16x16x32_bf16(ah, bl8, p[kt][fn], 0, 0, 0);
      }
    }
#pragma unroll
    for (int fn = 0; fn < 4; ++fn)
#pragma unroll
      for (int j = 0; j < 4; ++j) {
        float e = __expf(p[kt][fn][j] * 0.125f);
        p[kt][fn][j] = e;
        zpart[j] += e;
      }
  }

  float invz[4];
#pragma unroll
  for (int j = 0; j < 4; ++j) {
    float z = zpart[j];
    z += __shfl_xor(z, 1);
    z += __shfl_xor(z, 2);
    z += __shfl_xor(z, 4);
    z += __shfl_xor(z, 8);
    invz[j] = 1.f / z;
  }

#pragma unroll
  for (int kt = 0; kt < 9; ++kt)
#pragma unroll
    for (int fn = 0; fn < 4; ++fn) {
      float cp = p[kt][fn][0] * invz[0] + p[kt][fn][1] * invz[1] +
                 p[kt][fn][2] * invz[2] + p[kt][fn][3] * invz[3];
      cp += __shfl_xor(cp, 16);
      cp += __shfl_xor(cp, 32);
      if (lk == 0) atomicAdd(&c_lds[kt * 64 + fn * 16 + lm], cp);
    }
  __syncthreads();
  for (int i = tid; i < L_; i += 256)
    atomicAdd(&c[(size_t)bh * L_ + i], c_lds[i]);
}

// ---------------------------------------------------------------------------
// Kernel 3: t[b, h*64+e] += sum_{k in chunk} c[b,h,k] * V[b,h,k,e]
// 4-way k-split (grid y) + atomicAdd for 4x parallelism; t pre-zeroed.
// ---------------------------------------------------------------------------
__global__ void cv_kernel(const float* __restrict__ c,
                          const float* __restrict__ Vv,
                          float* __restrict__ t) {
  const int bh = blockIdx.x;
  const int chunk = blockIdx.y;          // 0..3, 144 k each
  const int e = threadIdx.x;
  const float* cb = c + (size_t)bh * L_;
  const float* Vb = Vv + (size_t)bh * L_ * HD_;
  float acc = 0.f;
  const int k0 = chunk * 144;
  for (int k = k0; k < k0 + 144; ++k)
    acc = fmaf(cb[k], Vb[(size_t)k * HD_ + e], acc);
  int b = bh / H_, h = bh - (bh / H_) * H_;
  atomicAdd(&t[(size_t)b * D_ + h * HD_ + e], acc);
}

// ---------------------------------------------------------------------------
// Kernel 4: s[b,d] = sum_d' t[b,d'] * Wproj[d,d'] + L*bproj[d]
// ---------------------------------------------------------------------------
__global__ __launch_bounds__(768) void proj_kernel(
    const float* __restrict__ t, const float* __restrict__ Wp,
    const float* __restrict__ bp, float* __restrict__ s) {
  __shared__ float tl[768];
  const int b = blockIdx.x, d = threadIdx.x;
  tl[d] = t[(size_t)b * D_ + d];
  __syncthreads();
  float acc = (float)L_ * bp[d];
  const float* wrow = Wp + (size_t)d * D_;
  for (int dp = 0; dp < D_; ++dp) acc = fmaf(tl[dp], wrow[dp], acc);
  s[(size_t)b * D_ + d] = acc;
}

// ---------------------------------------------------------------------------
// Kernel 5: sim[b,v] = sum_d s[b,d] * word_emd[v,d]. Streaming, depth-4
// prefetch (8 KB/wave in flight). Layout identical to round-10 version.
// ---------------------------------------------------------------------------
#define SIM_COMPUTE(K, CWA, CWB)                                            \
  {                                                                         \
    const float* sbp = &s2[((K) * 16 + p) * 36];                            \
    float4 sj[8];                                                           \
    _Pragma("unroll")                                                       \
    for (int jj = 0; jj < 8; ++jj) sj[jj] = *(const float4*)(sbp + jj * 4); \
    float ca4[4] = {CWA.x, CWA.y, CWA.z, CWA.w};                            \
    float cb4[4] = {CWB.x, CWB.y, CWB.z, CWB.w};                            \
    _Pragma("unroll")                                                       \
    for (int j = 0; j < 4; ++j) {                                           \
      accA[0] = fmaf(ca4[j], sj[2 * j].x, accA[0]);                         \
      accA[1] = fmaf(ca4[j], sj[2 * j].y, accA[1]);                         \
      accA[2] = fmaf(ca4[j], sj[2 * j].z, accA[2]);                         \
      accA[3] = fmaf(ca4[j], sj[2 * j].w, accA[3]);                         \
      accA[4] = fmaf(ca4[j], sj[2 * j + 1].x, accA[4]);                     \
      accA[5] = fmaf(ca4[j], sj[2 * j + 1].y, accA[5]);                     \
      accA[6] = fmaf(ca4[j], sj[2 * j + 1].z, accA[6]);                     \
      accA[7] = fmaf(ca4[j], sj[2 * j + 1].w, accA[7]);                     \
      accB[0] = fmaf(cb4[j], sj[2 * j].x, accB[0]);                         \
      accB[1] = fmaf(cb4[j], sj[2 * j].y, accB[1]);                         \
      accB[2] = fmaf(cb4[j], sj[2 * j].z, accB[2]);                         \
      accB[3] = fmaf(cb4[j], sj[2 * j].w, accB[3]);                         \
      accB[4] = fmaf(cb4[j], sj[2 * j + 1].x, accB[4]);                     \
      accB[5] = fmaf(cb4[j], sj[2 * j + 1].y, accB[5]);                     \
      accB[6] = fmaf(cb4[j], sj[2 * j + 1].z, accB[6]);                     \
      accB[7] = fmaf(cb4[j], sj[2 * j + 1].w, accB[7]);                     \
    }                                                                       \
  }

#define SIM_STEP(K, SA, SB)                                                 \
  {                                                                         \
    float4 cwa = SA, cwb = SB;                                              \
    if ((K) + 4 < 12) {                                                     \
      SA = *(const float4*)(wpA + ((K) + 4) * 64);                          \
      SB = *(const float4*)(wpB + ((K) + 4) * 64);                          \
    }                                                                       \
    SIM_COMPUTE(K, cwa, cwb)                                                \
  }

__global__ __launch_bounds__(256) void sim_kernel(
    const float* __restrict__ s, const float* __restrict__ w,
    float* __restrict__ sim) {
  __shared__ float s2[192 * 36];  // 27.6 KB
  const int tid = threadIdx.x;
  for (int e = tid; e < 6144; e += 256) {
    int b = e / 768;
    int d = e - b * 768;
    int k = d >> 6, pj = d & 63;
    int p = pj >> 2, j = pj & 3;
    s2[(k * 16 + p) * 36 + j * 8 + b] = s[e];
  }
  __syncthreads();

  const int wv = tid >> 6, l = tid & 63;
  const int g = l >> 4, p = l & 15;
  const int base = blockIdx.x * 32 + wv * 8;
  const int rA = base + g, rB = base + g + 4;
  const int cA = (rA < V_) ? rA : (V_ - 1);
  const int cB = (rB < V_) ? rB : (V_ - 1);
  const float* wpA = w + (size_t)cA * D_ + p * 4;
  const float* wpB = w + (size_t)cB * D_ + p * 4;

  float accA[8] = {}, accB[8] = {};
  float4 A0 = *(const float4*)(wpA);
  float4 B0 = *(const float4*)(wpB);
  float4 A1 = *(const float4*)(wpA + 64);
  float4 B1 = *(const float4*)(wpB + 64);
  float4 A2 = *(const float4*)(wpA + 128);
  float4 B2 = *(const float4*)(wpB + 128);
  float4 A3 = *(const float4*)(wpA + 192);
  float4 B3 = *(const float4*)(wpB + 192);

  SIM_STEP(0, A0, B0)
  SIM_STEP(1, A1, B1)
  SIM_STEP(2, A2, B2)
  SIM_STEP(3, A3, B3)
  SIM_STEP(4, A0, B0)
  SIM_STEP(5, A1, B1)
  SIM_STEP(6, A2, B2)
  SIM_STEP(7, A3, B3)
  SIM_STEP(8, A0, B0)
  SIM_STEP(9, A1, B1)
  SIM_STEP(10, A2, B2)
  SIM_STEP(11, A3, B3)

  // reduce over the 16 lanes of the group (xor masks 1,2,4,8 stay in-group)
#pragma unroll
  for (int off = 1; off < 16; off <<= 1) {
#pragma unroll
    for (int b = 0; b < 8; ++b) {
      accA[b] += __shfl_xor(accA[b], off);
      accB[b] += __shfl_xor(accB[b], off);
    }
  }
  if (p == 0) {
#pragma unroll
    for (int b = 0; b < 8; ++b) {
      if (rA < V_) sim[(size_t)b * V_ + rA] = accA[b];
      if (rB < V_) sim[(size_t)b * V_ + rB] = accB[b];
    }
  }
}

// ---------------------------------------------------------------------------
// Kernel 6a: per-chunk local top-10.
// ---------------------------------------------------------------------------
__global__ __launch_bounds__(256) void topk_stage1(
    const float* __restrict__ sim, float* __restrict__ cv,
    int* __restrict__ ci) {
  __shared__ float vals[CHUNK_SZ_];
  __shared__ float bv[256];
  __shared__ int bi[256];
  const int chunk = blockIdx.x, b = blockIdx.y, tid = threadIdx.x;
  const int base = chunk * CHUNK_SZ_;
  const float* row = sim + (size_t)b * V_;
  for (int i = tid; i < CHUNK_SZ_; i += 256) {
    int v = base + i;
    vals[i] = (v < V_) ? row[v] : -INFINITY;
  }
  __syncthreads();
  for (int k = 0; k < TOPK_; ++k) {
    float best = -INFINITY;
    int besti = CHUNK_SZ_;
    for (int i = tid; i < CHUNK_SZ_; i += 256) {
      float x = vals[i];
      if (x > best) { best = x; besti = i; }
    }
    bv[tid] = best; bi[tid] = besti;
    __syncthreads();
    for (int off = 128; off > 0; off >>= 1) {
      if (tid < off) {
        float ov = bv[tid + off]; int oi = bi[tid + off];
        if (ov > bv[tid] || (ov == bv[tid] && oi < bi[tid])) {
          bv[tid] = ov; bi[tid] = oi;
        }
      }
      __syncthreads();
    }
    if (tid == 0) {
      int slot = (b * CHUNKS_ + chunk) * TOPK_ + k;
      cv[slot] = bv[0];
      ci[slot] = base + bi[0];
      if (bi[0] < CHUNK_SZ_) vals[bi[0]] = -INFINITY;
    }
    __syncthreads();
  }
}

// ---------------------------------------------------------------------------
// Kernel 6b: reduce 64 chunks x 10 candidates -> global top-10 per batch.
// ---------------------------------------------------------------------------
__global__ __launch_bounds__(256) void topk_stage2(
    const float* __restrict__ cv, const int* __restrict__ ci,
    int* __restrict__ topk) {
  const int NC = CHUNKS_ * TOPK_;  // 640
  __shared__ float vals[CHUNKS_ * TOPK_];
  __shared__ int gidx[CHUNKS_ * TOPK_];
  __shared__ float bv[256];
  __shared__ int bi[256];
  const int b = blockIdx.x, tid = threadIdx.x;
  for (int i = tid; i < NC; i += 256) {
    vals[i] = cv[(size_t)b * NC + i];
    gidx[i] = ci[(size_t)b * NC + i];
  }
  __syncthreads();
  for (int k = 0; k < TOPK_; ++k) {
    float best = -INFINITY;
    int bslot = NC;
    for (int i = tid; i < NC; i += 256) {
      float x = vals[i];
      if (x > best) { best = x; bslot = i; }
    }
    bv[tid] = best; bi[tid] = bslot;
    __syncthreads();
    for (int off = 128; off > 0; off >>= 1) {
      if (tid < off) {
        float ov = bv[tid + off]; int oi = bi[tid + off];
        if (ov > bv[tid] || (ov == bv[tid] && oi < bi[tid])) {
          bv[tid] = ov; bi[tid] = oi;
        }
      }
      __syncthreads();
    }
    if (tid == 0) {
      int slot = bi[0];
      topk[b * TOPK_ + k] = (slot < NC) ? gidx[slot] : 0;
      if (slot < NC) vals[slot] = -INFINITY;
    }
    __syncthreads();
  }
}

// ---------------------------------------------------------------------------
// Kernel 7: gather word_emd rows -> output [B, K, D]
// ---------------------------------------------------------------------------
__global__ void gather_kernel(const int* __restrict__ topk,
                              const float* __restrict__ w,
                              float* __restrict__ out) {
  const int bk = blockIdx.x;
  const int idx = topk[bk];
  const int t4 = threadIdx.x << 2;
  *(float4*)(out + (size_t)bk * D_ + t4) =
      *(const float4*)(w + (size_t)idx * D_ + t4);
}

extern "C" void kernel_launch(void* const* d_in, const int* in_sizes, int n_in,
                              void* d_out, int out_size, void* d_ws,
                              size_t ws_size, hipStream_t stream) {
  const float* prompt = (const float*)d_in[0];
  const float* enc    = (const float*)d_in[1];
  const float* wemd   = (const float*)d_in[2];
  const float* Wqkv   = (const float*)d_in[3];
  const float* Wproj  = (const float*)d_in[4];
  const float* bproj  = (const float*)d_in[5];
  float* out = (float*)d_out;

  float* ws = (float*)d_ws;
  const size_t QSZ = (size_t)B_ * H_ * L_ * HD_;  // 3,538,944
  float* Vv   = ws;                        // fp32 V
  float* c    = Vv + QSZ;                  // 96*576 = 55,296
  float* t    = c + (size_t)B_ * H_ * L_;  // 6144
  float* s    = t + (size_t)B_ * D_;       // 6144
  float* sim  = s + (size_t)B_ * D_;       // 8*50257 = 402,056
  float* cand_v = sim + (size_t)B_ * V_;   // 8*640 = 5120
  int* cand_i   = (int*)(cand_v + (size_t)B_ * CHUNKS_ * TOPK_);
  int* topk     = cand_i + (size_t)B_ * CHUNKS_ * TOPK_;
  unsigned short* Qhi = (unsigned short*)(topk + B_ * TOPK_ + 64);
  unsigned short* Qlo = Qhi + QSZ;
  unsigned short* Khi = Qlo + QSZ;
  unsigned short* Klo = Khi + QSZ;
  unsigned short* Ahi = Klo + QSZ;
  unsigned short* Alo = Ahi + (size_t)M_QKV * K_QKV;
  unsigned short* Bhi = Alo + (size_t)M_QKV * K_QKV;
  unsigned short* Blo = Bhi + (size_t)N_QKV * K_QKV;

  // zero c AND t (contiguous) — cv now accumulates into t with atomics
  hipMemsetAsync(c, 0, ((size_t)B_ * H_ * L_ + (size_t)B_ * D_) * sizeof(float),
                 stream);

  const int NCONV = (M_QKV * K_QKV + N_QKV * K_QKV) / 4;  // 1,327,104
  convert_split<<<(NCONV + 255) / 256, 256, 0, stream>>>(
      prompt, enc, Wqkv, Ahi, Alo, Bhi, Blo);
  qkv_mfma<<<(M_QKV / 64) * (N_QKV / 128), 256, 0, stream>>>(
      Ahi, Alo, Bhi, Blo, Qhi, Qlo, Khi, Klo, Vv);
  attn_mfma<<<dim3(9, 96), 256, 0, stream>>>(Qhi, Qlo, Khi, Klo, c);
  cv_kernel<<<dim3(96, 4), 64, 0, stream>>>(c, Vv, t);
  proj_kernel<<<8, 768, 0, stream>>>(t, Wproj, bproj, s);
  sim_kernel<<<(V_ + 31) / 32, 256, 0, stream>>>(s, wemd, sim);
  topk_stage1<<<dim3(CHUNKS_, B_), 256, 0, stream>>>(sim, cand_v, cand_i);
  topk_stage2<<<B_, 256, 0, stream>>>(cand_v, cand_i, topk);
  gather_kernel<<<80, 192, 0, stream>>>(topk, wemd, out);
}

// Round 13
// 202.769 us; speedup vs baseline: 1.4789x; 1.3354x over previous
//
#include <hip/hip_runtime.h>
#include <math.h>

#define B_ 8
#define LP_ 64
#define LS_ 512
#define L_ 576
#define D_ 768
#define H_ 12
#define HD_ 64
#define V_ 50257
#define TOPK_ 10
#define CHUNKS_ 64
#define CHUNK_SZ_ 786  // ceil(V_/CHUNKS_); 64*786 = 50304 >= 50257

#define M_QKV 4608   // B_*L_
#define N_QKV 2304   // 3*D_
#define K_QKV 768

typedef __attribute__((ext_vector_type(8))) short bhalf8;
typedef __attribute__((ext_vector_type(4))) float floatx4;

#define GLOAD16(gptr, lptr)                                              \
  __builtin_amdgcn_global_load_lds(                                      \
      (const __attribute__((address_space(1))) unsigned int*)(gptr),     \
      (__attribute__((address_space(3))) unsigned int*)(lptr), 16, 0, 0)

// ---------------------------------------------------------------------------
// bf16 hi/lo split: x = hi + lo, hi = RNE-bf16(x), lo = RNE-bf16(x - hi).
// ---------------------------------------------------------------------------
__device__ inline void bf16split(float f, unsigned short& h, unsigned short& lo) {
  unsigned int u = __float_as_uint(f);
  unsigned short hb = (unsigned short)((u + 0x7FFFu + ((u >> 16) & 1u)) >> 16);
  float hf = __uint_as_float(((unsigned int)hb) << 16);
  float lf = f - hf;
  unsigned int ul = __float_as_uint(lf);
  unsigned short lb = (unsigned short)((ul + 0x7FFFu + ((ul >> 16) & 1u)) >> 16);
  h = hb; lo = lb;
}

// ---------------------------------------------------------------------------
// Kernel 0: build Ahi/Alo (x = concat(prompt,enc)) and Bhi/Blo (= Wqkv).
// ---------------------------------------------------------------------------
__global__ __launch_bounds__(256) void convert_split(
    const float* __restrict__ prompt, const float* __restrict__ enc,
    const float* __restrict__ Wqkv,
    unsigned short* __restrict__ Ahi, unsigned short* __restrict__ Alo,
    unsigned short* __restrict__ Bhi, unsigned short* __restrict__ Blo) {
  const int NA4 = M_QKV * K_QKV / 4;  // 884736
  const int NB4 = N_QKV * K_QKV / 4;  // 442368
  int i = blockIdx.x * 256 + threadIdx.x;
  if (i >= NA4 + NB4) return;
  const float* src;
  unsigned short *dh, *dl;
  int row, c4;
  if (i < NA4) {
    row = i / (K_QKV / 4);
    c4 = (i - row * (K_QKV / 4)) * 4;
    int b = row / L_, ll = row - (row / L_) * L_;
    src = (ll < LP_) ? (prompt + ((size_t)b * LP_ + ll) * D_ + c4)
                     : (enc + ((size_t)b * LS_ + (ll - LP_)) * D_ + c4);
    dh = Ahi + (size_t)row * K_QKV + c4;
    dl = Alo + (size_t)row * K_QKV + c4;
  } else {
    int j = i - NA4;
    row = j / (K_QKV / 4);
    c4 = (j - row * (K_QKV / 4)) * 4;
    src = Wqkv + (size_t)row * K_QKV + c4;
    dh = Bhi + (size_t)row * K_QKV + c4;
    dl = Blo + (size_t)row * K_QKV + c4;
  }
  float4 v = *(const float4*)src;
  ushort4 hv, lv;
  bf16split(v.x, hv.x, lv.x);
  bf16split(v.y, hv.y, lv.y);
  bf16split(v.z, hv.z, lv.z);
  bf16split(v.w, hv.w, lv.w);
  *(ushort4*)dh = hv;
  *(ushort4*)dl = lv;
}

// ---------------------------------------------------------------------------
// Kernel 1: QKV projection, split-bf16 MFMA, fused single K-pass.
// Tile 64(M)x128(N), BK=64 -> 12 K-steps (round-12 verified: drain-count
// halving cut qkv ~110 -> ~83us). LDS 48 KB single buffer.
// ---------------------------------------------------------------------------
__global__ __launch_bounds__(256) void qkv_mfma(
    const unsigned short* __restrict__ Ahi, const unsigned short* __restrict__ Alo,
    const unsigned short* __restrict__ Bhi, const unsigned short* __restrict__ Blo,
    unsigned short* __restrict__ Qhi, unsigned short* __restrict__ Qlo,
    unsigned short* __restrict__ Khi, unsigned short* __restrict__ Klo,
    float* __restrict__ Vv) {
  __shared__ unsigned short Ath[64 * 64];    // 8 KB each A buffer
  __shared__ unsigned short Atl[64 * 64];
  __shared__ unsigned short Bth[128 * 64];   // 16 KB each B buffer
  __shared__ unsigned short Btl[128 * 64];   // total 48 KB
  const int flat = blockIdx.x;
  const int swz = (flat & 7) * 162 + (flat >> 3);  // 1296 = 8 XCD x 162
  const int bx = swz % 18, by = swz / 18;          // bx<18 (N), by<72 (M)
  const int n0 = bx * 128, m0 = by * 64;
  const int tid = threadIdx.x;
  const int l = tid & 63;
  const int w = tid >> 6;          // wave 0..3, owns N-cols w*32..+32

  floatx4 acc[4][2];
#pragma unroll
  for (int i = 0; i < 4; ++i)
#pragma unroll
    for (int j = 0; j < 2; ++j) acc[i][j] = (floatx4){0.f, 0.f, 0.f, 0.f};

  const int r8 = l >> 3;                 // row within 8-row gload group
  const int cs = (l & 7) ^ r8;           // pre-swizzled source 16B chunk
  const int lm = l & 15;                 // fragment row/col within 16
  const int lk = l >> 4;                 // fragment k-group 0..3

  for (int kt = 0; kt < 12; ++kt) {
    const int kk0 = kt * 64;
    __syncthreads();
#pragma unroll
    for (int i = 0; i < 2; ++i) {  // A: 64 rows, 8 groups, 2 per wave
      const int row = w * 16 + i * 8;
      const size_t ga = (size_t)(m0 + row + r8) * K_QKV + kk0 + cs * 8;
      GLOAD16(Ahi + ga, &Ath[row * 64]);
      GLOAD16(Alo + ga, &Atl[row * 64]);
    }
#pragma unroll
    for (int i = 0; i < 4; ++i) {  // B: 128 rows, 16 groups, 4 per wave
      const int row = w * 32 + i * 8;
      const size_t gb = (size_t)(n0 + row + r8) * K_QKV + kk0 + cs * 8;
      GLOAD16(Bhi + gb, &Bth[row * 64]);
      GLOAD16(Blo + gb, &Btl[row * 64]);
    }
    __syncthreads();

#pragma unroll
    for (int s = 0; s < 2; ++s) {
      bhalf8 ah[4], al[4], bh8[2], bl8[2];
#pragma unroll
      for (int f = 0; f < 4; ++f) {
        const int ma = f * 16 + lm;
        const int ca = (s * 4 + lk) ^ (ma & 7);
        ah[f] = *(const bhalf8*)&Ath[ma * 64 + ca * 8];
        al[f] = *(const bhalf8*)&Atl[ma * 64 + ca * 8];
      }
#pragma unroll
      for (int f = 0; f < 2; ++f) {
        const int nb = w * 32 + f * 16 + lm;
        const int cb2 = (s * 4 + lk) ^ (nb & 7);
        bh8[f] = *(const bhalf8*)&Bth[nb * 64 + cb2 * 8];
        bl8[f] = *(const bhalf8*)&Btl[nb * 64 + cb2 * 8];
      }
#pragma unroll
      for (int fm = 0; fm < 4; ++fm)
#pragma unroll
        for (int fn = 0; fn < 2; ++fn) {
          acc[fm][fn] = __builtin_amdgcn_mfma_f32_16x16x32_bf16(
              ah[fm], bh8[fn], acc[fm][fn], 0, 0, 0);
          acc[fm][fn] = __builtin_amdgcn_mfma_f32_16x16x32_bf16(
              al[fm], bh8[fn], acc[fm][fn], 0, 0, 0);
          acc[fm][fn] = __builtin_amdgcn_mfma_f32_16x16x32_bf16(
              ah[fm], bl8[fn], acc[fm][fn], 0, 0, 0);
        }
    }
  }

  // C write: row m = lk*4 + j, col n = lm within each 16x16 fragment.
#pragma unroll
  for (int fm = 0; fm < 4; ++fm) {
#pragma unroll
    for (int fn = 0; fn < 2; ++fn) {
#pragma unroll
      for (int j = 0; j < 4; ++j) {
        int m = m0 + fm * 16 + lk * 4 + j;
        int n = n0 + w * 32 + fn * 16 + lm;
        int b = m / L_;
        int ll = m - b * L_;
        int part = n / D_;
        int rem = n - part * D_;
        int h = rem >> 6, e = rem & 63;
        size_t idx = (((size_t)b * H_ + h) * L_ + ll) * HD_ + e;
        float val = acc[fm][fn][j];
        if (part == 2) {
          Vv[idx] = val;
        } else {
          unsigned short hv, lv;
          bf16split(val, hv, lv);
          if (part == 0) { Qhi[idx] = hv; Qlo[idx] = lv; }
          else           { Khi[idx] = hv; Klo[idx] = lv; }
        }
      }
    }
  }
}

// ---------------------------------------------------------------------------
// Kernel 2: attention column sums via split-bf16 MFMA (round-6 single-buffer).
// ---------------------------------------------------------------------------
__global__ __launch_bounds__(256, 2) void attn_mfma(
    const unsigned short* __restrict__ Qhi, const unsigned short* __restrict__ Qlo,
    const unsigned short* __restrict__ Khi, const unsigned short* __restrict__ Klo,
    float* __restrict__ c) {
  __shared__ unsigned short Qh[64 * 64], Ql[64 * 64];  // 8 KB each
  __shared__ unsigned short Kh[64 * 64], Kl[64 * 64];
  __shared__ float c_lds[L_];
  const int qt = blockIdx.x;   // 0..8
  const int bh = blockIdx.y;   // 0..95
  const int tid = threadIdx.x;
  const int w = tid >> 6, l = tid & 63;
  const int lm = l & 15, lk = l >> 4;
  const int r8 = l >> 3;
  const int cs = (l & 7) ^ r8;

  for (int i = tid; i < L_; i += 256) c_lds[i] = 0.f;

  {
    const size_t gbase = ((size_t)bh * L_ + qt * 64) * HD_;
#pragma unroll
    for (int i = 0; i < 2; ++i) {
      int row = w * 16 + i * 8;
      GLOAD16(Qhi + gbase + (size_t)(row + r8) * HD_ + cs * 8, &Qh[row * 64]);
      GLOAD16(Qlo + gbase + (size_t)(row + r8) * HD_ + cs * 8, &Ql[row * 64]);
    }
  }

  floatx4 p[9][4];
#pragma unroll
  for (int kt = 0; kt < 9; ++kt)
#pragma unroll
    for (int fn = 0; fn < 4; ++fn) p[kt][fn] = (floatx4){0.f, 0.f, 0.f, 0.f};
  float zpart[4] = {0.f, 0.f, 0.f, 0.f};

#pragma unroll
  for (int kt = 0; kt < 9; ++kt) {
    __syncthreads();
    const size_t kb = ((size_t)bh * L_ + kt * 64) * HD_;
#pragma unroll
    for (int i = 0; i < 2; ++i) {
      int row = w * 16 + i * 8;
      GLOAD16(Khi + kb + (size_t)(row + r8) * HD_ + cs * 8, &Kh[row * 64]);
      GLOAD16(Klo + kb + (size_t)(row + r8) * HD_ + cs * 8, &Kl[row * 64]);
    }
    __syncthreads();
#pragma unroll
    for (int s = 0; s < 2; ++s) {
      const int ma = w * 16 + lm;
      const int ca = (s * 4 + lk) ^ (ma & 7);
      bhalf8 ah = *(const bhalf8*)&Qh[ma * 64 + ca * 8];
      bhalf8 al = *(const bhalf8*)&Ql[ma * 64 + ca * 8];
#pragma unroll
      for (int fn = 0; fn < 4; ++fn) {
        const int nb = fn * 16 + lm;
        const int cb2 = (s * 4 + lk) ^ (nb & 7);
        bhalf8 bh8 = *(const bhalf8*)&Kh[nb * 64 + cb2 * 8];
        bhalf8 bl8 = *(const bhalf8*)&Kl[nb * 64 + cb2 * 8];
        p[kt][fn] = __builtin_amdgcn_mfma_f32_16x16x32_bf16(ah, bh8, p[kt][fn], 0, 0, 0);
        p[kt][fn] = __builtin_amdgcn_mfma_f32_16x16x32_bf16(al, bh8, p[kt][fn], 0, 0, 0);
        p[kt][fn] = __builtin_amdgcn_mfma_f32_16x16x32_bf16(ah, bl8, p[kt][fn], 0, 0, 0);
      }
    }
#pragma unroll
    for (int fn = 0; fn < 4; ++fn)
#pragma unroll
      for (int j = 0; j < 4; ++j) {
        float e = __expf(p[kt][fn][j] * 0.125f);
        p[kt][fn][j] = e;
        zpart[j] += e;
      }
  }

  float invz[4];
#pragma unroll
  for (int j = 0; j < 4; ++j) {
    float z = zpart[j];
    z += __shfl_xor(z, 1);
    z += __shfl_xor(z, 2);
    z += __shfl_xor(z, 4);
    z += __shfl_xor(z, 8);
    invz[j] = 1.f / z;
  }

#pragma unroll
  for (int kt = 0; kt < 9; ++kt)
#pragma unroll
    for (int fn = 0; fn < 4; ++fn) {
      float cp = p[kt][fn][0] * invz[0] + p[kt][fn][1] * invz[1] +
                 p[kt][fn][2] * invz[2] + p[kt][fn][3] * invz[3];
      cp += __shfl_xor(cp, 16);
      cp += __shfl_xor(cp, 32);
      if (lk == 0) atomicAdd(&c_lds[kt * 64 + fn * 16 + lm], cp);
    }
  __syncthreads();
  for (int i = tid; i < L_; i += 256)
    atomicAdd(&c[(size_t)bh * L_ + i], c_lds[i]);
}

// ---------------------------------------------------------------------------
// Kernel 3: t[b, h*64+e] += sum_{k in chunk} c[b,h,k] * V[b,h,k,e]
// ---------------------------------------------------------------------------
__global__ void cv_kernel(const float* __restrict__ c,
                          const float* __restrict__ Vv,
                          float* __restrict__ t) {
  const int bh = blockIdx.x;
  const int chunk = blockIdx.y;          // 0..3, 144 k each
  const int e = threadIdx.x;
  const float* cb = c + (size_t)bh * L_;
  const float* Vb = Vv + (size_t)bh * L_ * HD_;
  float acc = 0.f;
  const int k0 = chunk * 144;
  for (int k = k0; k < k0 + 144; ++k)
    acc = fmaf(cb[k], Vb[(size_t)k * HD_ + e], acc);
  int b = bh / H_, h = bh - (bh / H_) * H_;
  atomicAdd(&t[(size_t)b * D_ + h * HD_ + e], acc);
}

// ---------------------------------------------------------------------------
// Kernel 4: s[b,d] = sum_d' t[b,d'] * Wproj[d,d'] + L*bproj[d].
// REWRITTEN: was 8 blocks + stride-3KB uncoalesced reads (88us @ 0.8%
// occupancy). Now 192 blocks x 4 waves, one Wproj row per wave with
// coalesced float4 reads; t staged in LDS; 64-lane shfl reduce.
// ---------------------------------------------------------------------------
__global__ __launch_bounds__(256) void proj_kernel(
    const float* __restrict__ t, const float* __restrict__ Wp,
    const float* __restrict__ bp, float* __restrict__ s) {
  __shared__ float tl[B_ * D_];  // 24 KB
  const int tid = threadIdx.x;
  for (int i = tid; i < (B_ * D_) / 4; i += 256)
    ((float4*)tl)[i] = ((const float4*)t)[i];
  __syncthreads();

  const int wv = tid >> 6, l = tid & 63;
  const int d = blockIdx.x * 4 + wv;     // 0..767
  const float* wrow = Wp + (size_t)d * D_;
  float acc[B_] = {};
#pragma unroll
  for (int k = 0; k < 3; ++k) {
    const int off = k * 256 + l * 4;
    float4 w4 = *(const float4*)(wrow + off);
#pragma unroll
    for (int b = 0; b < B_; ++b) {
      float4 t4 = *(const float4*)&tl[b * D_ + off];
      acc[b] = fmaf(w4.x, t4.x, acc[b]);
      acc[b] = fmaf(w4.y, t4.y, acc[b]);
      acc[b] = fmaf(w4.z, t4.z, acc[b]);
      acc[b] = fmaf(w4.w, t4.w, acc[b]);
    }
  }
#pragma unroll
  for (int off = 1; off < 64; off <<= 1)
#pragma unroll
    for (int b = 0; b < B_; ++b) acc[b] += __shfl_xor(acc[b], off);
  if (l == 0) {
    float bias = (float)L_ * bp[d];
#pragma unroll
    for (int b = 0; b < B_; ++b) s[(size_t)b * D_ + d] = acc[b] + bias;
  }
}

// ---------------------------------------------------------------------------
// Kernel 5: sim[b,v] = sum_d s[b,d] * word_emd[v,d]. Streaming, depth-4
// prefetch (8 KB/wave in flight).
// ---------------------------------------------------------------------------
#define SIM_COMPUTE(K, CWA, CWB)                                            \
  {                                                                         \
    const float* sbp = &s2[((K) * 16 + p) * 36];                            \
    float4 sj[8];                                                           \
    _Pragma("unroll")                                                       \
    for (int jj = 0; jj < 8; ++jj) sj[jj] = *(const float4*)(sbp + jj * 4); \
    float ca4[4] = {CWA.x, CWA.y, CWA.z, CWA.w};                            \
    float cb4[4] = {CWB.x, CWB.y, CWB.z, CWB.w};                            \
    _Pragma("unroll")                                                       \
    for (int j = 0; j < 4; ++j) {                                           \
      accA[0] = fmaf(ca4[j], sj[2 * j].x, accA[0]);                         \
      accA[1] = fmaf(ca4[j], sj[2 * j].y, accA[1]);                         \
      accA[2] = fmaf(ca4[j], sj[2 * j].z, accA[2]);                         \
      accA[3] = fmaf(ca4[j], sj[2 * j].w, accA[3]);                         \
      accA[4] = fmaf(ca4[j], sj[2 * j + 1].x, accA[4]);                     \
      accA[5] = fmaf(ca4[j], sj[2 * j + 1].y, accA[5]);                     \
      accA[6] = fmaf(ca4[j], sj[2 * j + 1].z, accA[6]);                     \
      accA[7] = fmaf(ca4[j], sj[2 * j + 1].w, accA[7]);                     \
      accB[0] = fmaf(cb4[j], sj[2 * j].x, accB[0]);                         \
      accB[1] = fmaf(cb4[j], sj[2 * j].y, accB[1]);                         \
      accB[2] = fmaf(cb4[j], sj[2 * j].z, accB[2]);                         \
      accB[3] = fmaf(cb4[j], sj[2 * j].w, accB[3]);                         \
      accB[4] = fmaf(cb4[j], sj[2 * j + 1].x, accB[4]);                     \
      accB[5] = fmaf(cb4[j], sj[2 * j + 1].y, accB[5]);                     \
      accB[6] = fmaf(cb4[j], sj[2 * j + 1].z, accB[6]);                     \
      accB[7] = fmaf(cb4[j], sj[2 * j + 1].w, accB[7]);                     \
    }                                                                       \
  }

#define SIM_STEP(K, SA, SB)                                                 \
  {                                                                         \
    float4 cwa = SA, cwb = SB;                                              \
    if ((K) + 4 < 12) {                                                     \
      SA = *(const float4*)(wpA + ((K) + 4) * 64);                          \
      SB = *(const float4*)(wpB + ((K) + 4) * 64);                          \
    }                                                                       \
    SIM_COMPUTE(K, cwa, cwb)                                                \
  }

__global__ __launch_bounds__(256) void sim_kernel(
    const float* __restrict__ s, const float* __restrict__ w,
    float* __restrict__ sim) {
  __shared__ float s2[192 * 36];  // 27.6 KB
  const int tid = threadIdx.x;
  for (int e = tid; e < 6144; e += 256) {
    int b = e / 768;
    int d = e - b * 768;
    int k = d >> 6, pj = d & 63;
    int p = pj >> 2, j = pj & 3;
    s2[(k * 16 + p) * 36 + j * 8 + b] = s[e];
  }
  __syncthreads();

  const int wv = tid >> 6, l = tid & 63;
  const int g = l >> 4, p = l & 15;
  const int base = blockIdx.x * 32 + wv * 8;
  const int rA = base + g, rB = base + g + 4;
  const int cA = (rA < V_) ? rA : (V_ - 1);
  const int cB = (rB < V_) ? rB : (V_ - 1);
  const float* wpA = w + (size_t)cA * D_ + p * 4;
  const float* wpB = w + (size_t)cB * D_ + p * 4;

  float accA[8] = {}, accB[8] = {};
  float4 A0 = *(const float4*)(wpA);
  float4 B0 = *(const float4*)(wpB);
  float4 A1 = *(const float4*)(wpA + 64);
  float4 B1 = *(const float4*)(wpB + 64);
  float4 A2 = *(const float4*)(wpA + 128);
  float4 B2 = *(const float4*)(wpB + 128);
  float4 A3 = *(const float4*)(wpA + 192);
  float4 B3 = *(const float4*)(wpB + 192);

  SIM_STEP(0, A0, B0)
  SIM_STEP(1, A1, B1)
  SIM_STEP(2, A2, B2)
  SIM_STEP(3, A3, B3)
  SIM_STEP(4, A0, B0)
  SIM_STEP(5, A1, B1)
  SIM_STEP(6, A2, B2)
  SIM_STEP(7, A3, B3)
  SIM_STEP(8, A0, B0)
  SIM_STEP(9, A1, B1)
  SIM_STEP(10, A2, B2)
  SIM_STEP(11, A3, B3)

#pragma unroll
  for (int off = 1; off < 16; off <<= 1) {
#pragma unroll
    for (int b = 0; b < 8; ++b) {
      accA[b] += __shfl_xor(accA[b], off);
      accB[b] += __shfl_xor(accB[b], off);
    }
  }
  if (p == 0) {
#pragma unroll
    for (int b = 0; b < 8; ++b) {
      if (rA < V_) sim[(size_t)b * V_ + rA] = accA[b];
      if (rB < V_) sim[(size_t)b * V_ + rB] = accB[b];
    }
  }
}

// ---------------------------------------------------------------------------
// Kernel 6a: per-chunk local top-10.
// ---------------------------------------------------------------------------
__global__ __launch_bounds__(256) void topk_stage1(
    const float* __restrict__ sim, float* __restrict__ cv,
    int* __restrict__ ci) {
  __shared__ float vals[CHUNK_SZ_];
  __shared__ float bv[256];
  __shared__ int bi[256];
  const int chunk = blockIdx.x, b = blockIdx.y, tid = threadIdx.x;
  const int base = chunk * CHUNK_SZ_;
  const float* row = sim + (size_t)b * V_;
  for (int i = tid; i < CHUNK_SZ_; i += 256) {
    int v = base + i;
    vals[i] = (v < V_) ? row[v] : -INFINITY;
  }
  __syncthreads();
  for (int k = 0; k < TOPK_; ++k) {
    float best = -INFINITY;
    int besti = CHUNK_SZ_;
    for (int i = tid; i < CHUNK_SZ_; i += 256) {
      float x = vals[i];
      if (x > best) { best = x; besti = i; }
    }
    bv[tid] = best; bi[tid] = besti;
    __syncthreads();
    for (int off = 128; off > 0; off >>= 1) {
      if (tid < off) {
        float ov = bv[tid + off]; int oi = bi[tid + off];
        if (ov > bv[tid] || (ov == bv[tid] && oi < bi[tid])) {
          bv[tid] = ov; bi[tid] = oi;
        }
      }
      __syncthreads();
    }
    if (tid == 0) {
      int slot = (b * CHUNKS_ + chunk) * TOPK_ + k;
      cv[slot] = bv[0];
      ci[slot] = base + bi[0];
      if (bi[0] < CHUNK_SZ_) vals[bi[0]] = -INFINITY;
    }
    __syncthreads();
  }
}

// ---------------------------------------------------------------------------
// Kernel 6b: reduce 64 chunks x 10 candidates -> global top-10 per batch.
// ---------------------------------------------------------------------------
__global__ __launch_bounds__(256) void topk_stage2(
    const float* __restrict__ cv, const int* __restrict__ ci,
    int* __restrict__ topk) {
  const int NC = CHUNKS_ * TOPK_;  // 640
  __shared__ float vals[CHUNKS_ * TOPK_];
  __shared__ int gidx[CHUNKS_ * TOPK_];
  __shared__ float bv[256];
  __shared__ int bi[256];
  const int b = blockIdx.x, tid = threadIdx.x;
  for (int i = tid; i < NC; i += 256) {
    vals[i] = cv[(size_t)b * NC + i];
    gidx[i] = ci[(size_t)b * NC + i];
  }
  __syncthreads();
  for (int k = 0; k < TOPK_; ++k) {
    float best = -INFINITY;
    int bslot = NC;
    for (int i = tid; i < NC; i += 256) {
      float x = vals[i];
      if (x > best) { best = x; bslot = i; }
    }
    bv[tid] = best; bi[tid] = bslot;
    __syncthreads();
    for (int off = 128; off > 0; off >>= 1) {
      if (tid < off) {
        float ov = bv[tid + off]; int oi = bi[tid + off];
        if (ov > bv[tid] || (ov == bv[tid] && oi < bi[tid])) {
          bv[tid] = ov; bi[tid] = oi;
        }
      }
      __syncthreads();
    }
    if (tid == 0) {
      int slot = bi[0];
      topk[b * TOPK_ + k] = (slot < NC) ? gidx[slot] : 0;
      if (slot < NC) vals[slot] = -INFINITY;
    }
    __syncthreads();
  }
}

// ---------------------------------------------------------------------------
// Kernel 7: gather word_emd rows -> output [B, K, D]
// ---------------------------------------------------------------------------
__global__ void gather_kernel(const int* __restrict__ topk,
                              const float* __restrict__ w,
                              float* __restrict__ out) {
  const int bk = blockIdx.x;
  const int idx = topk[bk];
  const int t4 = threadIdx.x << 2;
  *(float4*)(out + (size_t)bk * D_ + t4) =
      *(const float4*)(w + (size_t)idx * D_ + t4);
}

extern "C" void kernel_launch(void* const* d_in, const int* in_sizes, int n_in,
                              void* d_out, int out_size, void* d_ws,
                              size_t ws_size, hipStream_t stream) {
  const float* prompt = (const float*)d_in[0];
  const float* enc    = (const float*)d_in[1];
  const float* wemd   = (const float*)d_in[2];
  const float* Wqkv   = (const float*)d_in[3];
  const float* Wproj  = (const float*)d_in[4];
  const float* bproj  = (const float*)d_in[5];
  float* out = (float*)d_out;

  float* ws = (float*)d_ws;
  const size_t QSZ = (size_t)B_ * H_ * L_ * HD_;  // 3,538,944
  float* Vv   = ws;                        // fp32 V
  float* c    = Vv + QSZ;                  // 96*576 = 55,296
  float* t    = c + (size_t)B_ * H_ * L_;  // 6144
  float* s    = t + (size_t)B_ * D_;       // 6144
  float* sim  = s + (size_t)B_ * D_;       // 8*50257 = 402,056
  float* cand_v = sim + (size_t)B_ * V_;   // 8*640 = 5120
  int* cand_i   = (int*)(cand_v + (size_t)B_ * CHUNKS_ * TOPK_);
  int* topk     = cand_i + (size_t)B_ * CHUNKS_ * TOPK_;
  unsigned short* Qhi = (unsigned short*)(topk + B_ * TOPK_ + 64);
  unsigned short* Qlo = Qhi + QSZ;
  unsigned short* Khi = Qlo + QSZ;
  unsigned short* Klo = Khi + QSZ;
  unsigned short* Ahi = Klo + QSZ;
  unsigned short* Alo = Ahi + (size_t)M_QKV * K_QKV;
  unsigned short* Bhi = Alo + (size_t)M_QKV * K_QKV;
  unsigned short* Blo = Bhi + (size_t)N_QKV * K_QKV;

  // zero c AND t (contiguous) — cv accumulates into t with atomics
  hipMemsetAsync(c, 0, ((size_t)B_ * H_ * L_ + (size_t)B_ * D_) * sizeof(float),
                 stream);

  const int NCONV = (M_QKV * K_QKV + N_QKV * K_QKV) / 4;  // 1,327,104
  convert_split<<<(NCONV + 255) / 256, 256, 0, stream>>>(
      prompt, enc, Wqkv, Ahi, Alo, Bhi, Blo);
  qkv_mfma<<<(M_QKV / 64) * (N_QKV / 128), 256, 0, stream>>>(
      Ahi, Alo, Bhi, Blo, Qhi, Qlo, Khi, Klo, Vv);
  attn_mfma<<<dim3(9, 96), 256, 0, stream>>>(Qhi, Qlo, Khi, Klo, c);
  cv_kernel<<<dim3(96, 4), 64, 0, stream>>>(c, Vv, t);
  proj_kernel<<<D_ / 4, 256, 0, stream>>>(t, Wproj, bproj, s);
  sim_kernel<<<(V_ + 31) / 32, 256, 0, stream>>>(s, wemd, sim);
  topk_stage1<<<dim3(CHUNKS_, B_), 256, 0, stream>>>(sim, cand_v, cand_i);
  topk_stage2<<<B_, 256, 0, stream>>>(cand_v, cand_i, topk);
  gather_kernel<<<80, 192, 0, stream>>>(topk, wemd, out);
}

// Round 14
// 200.975 us; speedup vs baseline: 1.4921x; 1.0089x over previous
//
#include <hip/hip_runtime.h>
#include <math.h>

#define B_ 8
#define LP_ 64
#define LS_ 512
#define L_ 576
#define D_ 768
#define H_ 12
#define HD_ 64
#define V_ 50257
#define TOPK_ 10
#define CHUNKS_ 64
#define CHUNK_SZ_ 786  // ceil(V_/CHUNKS_); 64*786 = 50304 >= 50257

#define M_QKV 4608   // B_*L_
#define N_QKV 2304   // 3*D_
#define K_QKV 768

typedef __attribute__((ext_vector_type(8))) short bhalf8;
typedef __attribute__((ext_vector_type(4))) float floatx4;

#define GLOAD16(gptr, lptr)                                              \
  __builtin_amdgcn_global_load_lds(                                      \
      (const __attribute__((address_space(1))) unsigned int*)(gptr),     \
      (__attribute__((address_space(3))) unsigned int*)(lptr), 16, 0, 0)

// ---------------------------------------------------------------------------
// bf16 hi/lo split: x = hi + lo, hi = RNE-bf16(x), lo = RNE-bf16(x - hi).
// ---------------------------------------------------------------------------
__device__ inline void bf16split(float f, unsigned short& h, unsigned short& lo) {
  unsigned int u = __float_as_uint(f);
  unsigned short hb = (unsigned short)((u + 0x7FFFu + ((u >> 16) & 1u)) >> 16);
  float hf = __uint_as_float(((unsigned int)hb) << 16);
  float lf = f - hf;
  unsigned int ul = __float_as_uint(lf);
  unsigned short lb = (unsigned short)((ul + 0x7FFFu + ((ul >> 16) & 1u)) >> 16);
  h = hb; lo = lb;
}

// ---------------------------------------------------------------------------
// Kernel 0: build Ahi/Alo (x = concat(prompt,enc)) and Bhi/Blo (= Wqkv).
// ---------------------------------------------------------------------------
__global__ __launch_bounds__(256) void convert_split(
    const float* __restrict__ prompt, const float* __restrict__ enc,
    const float* __restrict__ Wqkv,
    unsigned short* __restrict__ Ahi, unsigned short* __restrict__ Alo,
    unsigned short* __restrict__ Bhi, unsigned short* __restrict__ Blo) {
  const int NA4 = M_QKV * K_QKV / 4;  // 884736
  const int NB4 = N_QKV * K_QKV / 4;  // 442368
  int i = blockIdx.x * 256 + threadIdx.x;
  if (i >= NA4 + NB4) return;
  const float* src;
  unsigned short *dh, *dl;
  int row, c4;
  if (i < NA4) {
    row = i / (K_QKV / 4);
    c4 = (i - row * (K_QKV / 4)) * 4;
    int b = row / L_, ll = row - (row / L_) * L_;
    src = (ll < LP_) ? (prompt + ((size_t)b * LP_ + ll) * D_ + c4)
                     : (enc + ((size_t)b * LS_ + (ll - LP_)) * D_ + c4);
    dh = Ahi + (size_t)row * K_QKV + c4;
    dl = Alo + (size_t)row * K_QKV + c4;
  } else {
    int j = i - NA4;
    row = j / (K_QKV / 4);
    c4 = (j - row * (K_QKV / 4)) * 4;
    src = Wqkv + (size_t)row * K_QKV + c4;
    dh = Bhi + (size_t)row * K_QKV + c4;
    dl = Blo + (size_t)row * K_QKV + c4;
  }
  float4 v = *(const float4*)src;
  ushort4 hv, lv;
  bf16split(v.x, hv.x, lv.x);
  bf16split(v.y, hv.y, lv.y);
  bf16split(v.z, hv.z, lv.z);
  bf16split(v.w, hv.w, lv.w);
  *(ushort4*)dh = hv;
  *(ushort4*)dl = lv;
}

// ---------------------------------------------------------------------------
// Kernel 1: QKV projection, split-bf16 MFMA, fused single K-pass.
// Tile 64(M)x128(N), BK=64, 12 K-steps (round-12/13 verified best: ~86us,
// 570 TF effective — above the reference shape curve for this size).
// ---------------------------------------------------------------------------
__global__ __launch_bounds__(256) void qkv_mfma(
    const unsigned short* __restrict__ Ahi, const unsigned short* __restrict__ Alo,
    const unsigned short* __restrict__ Bhi, const unsigned short* __restrict__ Blo,
    unsigned short* __restrict__ Qhi, unsigned short* __restrict__ Qlo,
    unsigned short* __restrict__ Khi, unsigned short* __restrict__ Klo,
    float* __restrict__ Vv) {
  __shared__ unsigned short Ath[64 * 64];    // 8 KB each A buffer
  __shared__ unsigned short Atl[64 * 64];
  __shared__ unsigned short Bth[128 * 64];   // 16 KB each B buffer
  __shared__ unsigned short Btl[128 * 64];   // total 48 KB
  const int flat = blockIdx.x;
  const int swz = (flat & 7) * 162 + (flat >> 3);  // 1296 = 8 XCD x 162
  const int bx = swz % 18, by = swz / 18;          // bx<18 (N), by<72 (M)
  const int n0 = bx * 128, m0 = by * 64;
  const int tid = threadIdx.x;
  const int l = tid & 63;
  const int w = tid >> 6;          // wave 0..3, owns N-cols w*32..+32

  floatx4 acc[4][2];
#pragma unroll
  for (int i = 0; i < 4; ++i)
#pragma unroll
    for (int j = 0; j < 2; ++j) acc[i][j] = (floatx4){0.f, 0.f, 0.f, 0.f};

  const int r8 = l >> 3;                 // row within 8-row gload group
  const int cs = (l & 7) ^ r8;           // pre-swizzled source 16B chunk
  const int lm = l & 15;                 // fragment row/col within 16
  const int lk = l >> 4;                 // fragment k-group 0..3

  for (int kt = 0; kt < 12; ++kt) {
    const int kk0 = kt * 64;
    __syncthreads();
#pragma unroll
    for (int i = 0; i < 2; ++i) {  // A: 64 rows, 8 groups, 2 per wave
      const int row = w * 16 + i * 8;
      const size_t ga = (size_t)(m0 + row + r8) * K_QKV + kk0 + cs * 8;
      GLOAD16(Ahi + ga, &Ath[row * 64]);
      GLOAD16(Alo + ga, &Atl[row * 64]);
    }
#pragma unroll
    for (int i = 0; i < 4; ++i) {  // B: 128 rows, 16 groups, 4 per wave
      const int row = w * 32 + i * 8;
      const size_t gb = (size_t)(n0 + row + r8) * K_QKV + kk0 + cs * 8;
      GLOAD16(Bhi + gb, &Bth[row * 64]);
      GLOAD16(Blo + gb, &Btl[row * 64]);
    }
    __syncthreads();

#pragma unroll
    for (int s = 0; s < 2; ++s) {
      bhalf8 ah[4], al[4], bh8[2], bl8[2];
#pragma unroll
      for (int f = 0; f < 4; ++f) {
        const int ma = f * 16 + lm;
        const int ca = (s * 4 + lk) ^ (ma & 7);
        ah[f] = *(const bhalf8*)&Ath[ma * 64 + ca * 8];
        al[f] = *(const bhalf8*)&Atl[ma * 64 + ca * 8];
      }
#pragma unroll
      for (int f = 0; f < 2; ++f) {
        const int nb = w * 32 + f * 16 + lm;
        const int cb2 = (s * 4 + lk) ^ (nb & 7);
        bh8[f] = *(const bhalf8*)&Bth[nb * 64 + cb2 * 8];
        bl8[f] = *(const bhalf8*)&Btl[nb * 64 + cb2 * 8];
      }
#pragma unroll
      for (int fm = 0; fm < 4; ++fm)
#pragma unroll
        for (int fn = 0; fn < 2; ++fn) {
          acc[fm][fn] = __builtin_amdgcn_mfma_f32_16x16x32_bf16(
              ah[fm], bh8[fn], acc[fm][fn], 0, 0, 0);
          acc[fm][fn] = __builtin_amdgcn_mfma_f32_16x16x32_bf16(
              al[fm], bh8[fn], acc[fm][fn], 0, 0, 0);
          acc[fm][fn] = __builtin_amdgcn_mfma_f32_16x16x32_bf16(
              ah[fm], bl8[fn], acc[fm][fn], 0, 0, 0);
        }
    }
  }

  // C write: row m = lk*4 + j, col n = lm within each 16x16 fragment.
#pragma unroll
  for (int fm = 0; fm < 4; ++fm) {
#pragma unroll
    for (int fn = 0; fn < 2; ++fn) {
#pragma unroll
      for (int j = 0; j < 4; ++j) {
        int m = m0 + fm * 16 + lk * 4 + j;
        int n = n0 + w * 32 + fn * 16 + lm;
        int b = m / L_;
        int ll = m - b * L_;
        int part = n / D_;
        int rem = n - part * D_;
        int h = rem >> 6, e = rem & 63;
        size_t idx = (((size_t)b * H_ + h) * L_ + ll) * HD_ + e;
        float val = acc[fm][fn][j];
        if (part == 2) {
          Vv[idx] = val;
        } else {
          unsigned short hv, lv;
          bf16split(val, hv, lv);
          if (part == 0) { Qhi[idx] = hv; Qlo[idx] = lv; }
          else           { Khi[idx] = hv; Klo[idx] = lv; }
        }
      }
    }
  }
}

// ---------------------------------------------------------------------------
// Kernel 2: attention column sums via split-bf16 MFMA.
// KVBLK 64 -> 192: 3 K-steps instead of 9 (drain-count lever, verified on
// qkv in round 12). Per step per wave: 72 MFMA. LDS 66 KB (K hi/lo 48 +
// Q 16 + c_lds); still 2 blocks/CU (VGPR-bound at 2 regardless).
// ---------------------------------------------------------------------------
__global__ __launch_bounds__(256, 2) void attn_mfma(
    const unsigned short* __restrict__ Qhi, const unsigned short* __restrict__ Qlo,
    const unsigned short* __restrict__ Khi, const unsigned short* __restrict__ Klo,
    float* __restrict__ c) {
  __shared__ unsigned short Qh[64 * 64], Ql[64 * 64];    // 8 KB each
  __shared__ unsigned short Kh[192 * 64], Kl[192 * 64];  // 24 KB each
  __shared__ float c_lds[L_];
  const int qt = blockIdx.x;   // 0..8
  const int bh = blockIdx.y;   // 0..95
  const int tid = threadIdx.x;
  const int w = tid >> 6, l = tid & 63;
  const int lm = l & 15, lk = l >> 4;
  const int r8 = l >> 3;
  const int cs = (l & 7) ^ r8;

  for (int i = tid; i < L_; i += 256) c_lds[i] = 0.f;

  {
    const size_t gbase = ((size_t)bh * L_ + qt * 64) * HD_;
#pragma unroll
    for (int i = 0; i < 2; ++i) {
      int row = w * 16 + i * 8;
      GLOAD16(Qhi + gbase + (size_t)(row + r8) * HD_ + cs * 8, &Qh[row * 64]);
      GLOAD16(Qlo + gbase + (size_t)(row + r8) * HD_ + cs * 8, &Ql[row * 64]);
    }
  }

  floatx4 p[3][12];
#pragma unroll
  for (int kt = 0; kt < 3; ++kt)
#pragma unroll
    for (int fn = 0; fn < 12; ++fn) p[kt][fn] = (floatx4){0.f, 0.f, 0.f, 0.f};
  float zpart[4] = {0.f, 0.f, 0.f, 0.f};

#pragma unroll
  for (int kt = 0; kt < 3; ++kt) {
    __syncthreads();
    const size_t kb = ((size_t)bh * L_ + kt * 192) * HD_;
#pragma unroll
    for (int i = 0; i < 6; ++i) {  // 192 rows = 24 groups of 8; 6 per wave
      int row = w * 48 + i * 8;
      GLOAD16(Khi + kb + (size_t)(row + r8) * HD_ + cs * 8, &Kh[row * 64]);
      GLOAD16(Klo + kb + (size_t)(row + r8) * HD_ + cs * 8, &Kl[row * 64]);
    }
    __syncthreads();
#pragma unroll
    for (int s = 0; s < 2; ++s) {
      const int ma = w * 16 + lm;
      const int ca = (s * 4 + lk) ^ (ma & 7);
      bhalf8 ah = *(const bhalf8*)&Qh[ma * 64 + ca * 8];
      bhalf8 al = *(const bhalf8*)&Ql[ma * 64 + ca * 8];
#pragma unroll
      for (int fn = 0; fn < 12; ++fn) {
        const int nb = fn * 16 + lm;
        const int cb2 = (s * 4 + lk) ^ (nb & 7);
        bhalf8 bh8 = *(const bhalf8*)&Kh[nb * 64 + cb2 * 8];
        bhalf8 bl8 = *(const bhalf8*)&Kl[nb * 64 + cb2 * 8];
        p[kt][fn] = __builtin_amdgcn_mfma_f32_16x16x32_bf16(ah, bh8, p[kt][fn], 0, 0, 0);
        p[kt][fn] = __builtin_amdgcn_mfma_f32_16x16x32_bf16(al, bh8, p[kt][fn], 0, 0, 0);
        p[kt][fn] = __builtin_amdgcn_mfma_f32_16x16x32_bf16(ah, bl8, p[kt][fn], 0, 0, 0);
      }
    }
#pragma unroll
    for (int fn = 0; fn < 12; ++fn)
#pragma unroll
      for (int j = 0; j < 4; ++j) {
        float e = __expf(p[kt][fn][j] * 0.125f);
        p[kt][fn][j] = e;
        zpart[j] += e;
      }
  }

  float invz[4];
#pragma unroll
  for (int j = 0; j < 4; ++j) {
    float z = zpart[j];
    z += __shfl_xor(z, 1);
    z += __shfl_xor(z, 2);
    z += __shfl_xor(z, 4);
    z += __shfl_xor(z, 8);
    invz[j] = 1.f / z;
  }

#pragma unroll
  for (int kt = 0; kt < 3; ++kt)
#pragma unroll
    for (int fn = 0; fn < 12; ++fn) {
      float cp = p[kt][fn][0] * invz[0] + p[kt][fn][1] * invz[1] +
                 p[kt][fn][2] * invz[2] + p[kt][fn][3] * invz[3];
      cp += __shfl_xor(cp, 16);
      cp += __shfl_xor(cp, 32);
      if (lk == 0) atomicAdd(&c_lds[kt * 192 + fn * 16 + lm], cp);
    }
  __syncthreads();
  for (int i = tid; i < L_; i += 256)
    atomicAdd(&c[(size_t)bh * L_ + i], c_lds[i]);
}

// ---------------------------------------------------------------------------
// Kernel 3: t[b, h*64+e] += sum_{k in chunk} c[b,h,k] * V[b,h,k,e]
// ---------------------------------------------------------------------------
__global__ void cv_kernel(const float* __restrict__ c,
                          const float* __restrict__ Vv,
                          float* __restrict__ t) {
  const int bh = blockIdx.x;
  const int chunk = blockIdx.y;          // 0..3, 144 k each
  const int e = threadIdx.x;
  const float* cb = c + (size_t)bh * L_;
  const float* Vb = Vv + (size_t)bh * L_ * HD_;
  float acc = 0.f;
  const int k0 = chunk * 144;
  for (int k = k0; k < k0 + 144; ++k)
    acc = fmaf(cb[k], Vb[(size_t)k * HD_ + e], acc);
  int b = bh / H_, h = bh - (bh / H_) * H_;
  atomicAdd(&t[(size_t)b * D_ + h * HD_ + e], acc);
}

// ---------------------------------------------------------------------------
// Kernel 4: s[b,d] = sum_d' t[b,d'] * Wproj[d,d'] + L*bproj[d].
// 192 blocks x 4 waves, one Wproj row per wave, coalesced; round-13
// verified (88us -> ~6us).
// ---------------------------------------------------------------------------
__global__ __launch_bounds__(256) void proj_kernel(
    const float* __restrict__ t, const float* __restrict__ Wp,
    const float* __restrict__ bp, float* __restrict__ s) {
  __shared__ float tl[B_ * D_];  // 24 KB
  const int tid = threadIdx.x;
  for (int i = tid; i < (B_ * D_) / 4; i += 256)
    ((float4*)tl)[i] = ((const float4*)t)[i];
  __syncthreads();

  const int wv = tid >> 6, l = tid & 63;
  const int d = blockIdx.x * 4 + wv;     // 0..767
  const float* wrow = Wp + (size_t)d * D_;
  float acc[B_] = {};
#pragma unroll
  for (int k = 0; k < 3; ++k) {
    const int off = k * 256 + l * 4;
    float4 w4 = *(const float4*)(wrow + off);
#pragma unroll
    for (int b = 0; b < B_; ++b) {
      float4 t4 = *(const float4*)&tl[b * D_ + off];
      acc[b] = fmaf(w4.x, t4.x, acc[b]);
      acc[b] = fmaf(w4.y, t4.y, acc[b]);
      acc[b] = fmaf(w4.z, t4.z, acc[b]);
      acc[b] = fmaf(w4.w, t4.w, acc[b]);
    }
  }
#pragma unroll
  for (int off = 1; off < 64; off <<= 1)
#pragma unroll
    for (int b = 0; b < B_; ++b) acc[b] += __shfl_xor(acc[b], off);
  if (l == 0) {
    float bias = (float)L_ * bp[d];
#pragma unroll
    for (int b = 0; b < B_; ++b) s[(size_t)b * D_ + d] = acc[b] + bias;
  }
}

// ---------------------------------------------------------------------------
// Kernel 5: sim[b,v] = sum_d s[b,d] * word_emd[v,d]. Streaming, depth-4
// prefetch (8 KB/wave in flight).
// ---------------------------------------------------------------------------
#define SIM_COMPUTE(K, CWA, CWB)                                            \
  {                                                                         \
    const float* sbp = &s2[((K) * 16 + p) * 36];                            \
    float4 sj[8];                                                           \
    _Pragma("unroll")                                                       \
    for (int jj = 0; jj < 8; ++jj) sj[jj] = *(const float4*)(sbp + jj * 4); \
    float ca4[4] = {CWA.x, CWA.y, CWA.z, CWA.w};                            \
    float cb4[4] = {CWB.x, CWB.y, CWB.z, CWB.w};                            \
    _Pragma("unroll")                                                       \
    for (int j = 0; j < 4; ++j) {                                           \
      accA[0] = fmaf(ca4[j], sj[2 * j].x, accA[0]);                         \
      accA[1] = fmaf(ca4[j], sj[2 * j].y, accA[1]);                         \
      accA[2] = fmaf(ca4[j], sj[2 * j].z, accA[2]);                         \
      accA[3] = fmaf(ca4[j], sj[2 * j].w, accA[3]);                         \
      accA[4] = fmaf(ca4[j], sj[2 * j + 1].x, accA[4]);                     \
      accA[5] = fmaf(ca4[j], sj[2 * j + 1].y, accA[5]);                     \
      accA[6] = fmaf(ca4[j], sj[2 * j + 1].z, accA[6]);                     \
      accA[7] = fmaf(ca4[j], sj[2 * j + 1].w, accA[7]);                     \
      accB[0] = fmaf(cb4[j], sj[2 * j].x, accB[0]);                         \
      accB[1] = fmaf(cb4[j], sj[2 * j].y, accB[1]);                         \
      accB[2] = fmaf(cb4[j], sj[2 * j].z, accB[2]);                         \
      accB[3] = fmaf(cb4[j], sj[2 * j].w, accB[3]);                         \
      accB[4] = fmaf(cb4[j], sj[2 * j + 1].x, accB[4]);                     \
      accB[5] = fmaf(cb4[j], sj[2 * j + 1].y, accB[5]);                     \
      accB[6] = fmaf(cb4[j], sj[2 * j + 1].z, accB[6]);                     \
      accB[7] = fmaf(cb4[j], sj[2 * j + 1].w, accB[7]);                     \
    }                                                                       \
  }

#define SIM_STEP(K, SA, SB)                                                 \
  {                                                                         \
    float4 cwa = SA, cwb = SB;                                              \
    if ((K) + 4 < 12) {                                                     \
      SA = *(const float4*)(wpA + ((K) + 4) * 64);                          \
      SB = *(const float4*)(wpB + ((K) + 4) * 64);                          \
    }                                                                       \
    SIM_COMPUTE(K, cwa, cwb)                                                \
  }

__global__ __launch_bounds__(256) void sim_kernel(
    const float* __restrict__ s, const float* __restrict__ w,
    float* __restrict__ sim) {
  __shared__ float s2[192 * 36];  // 27.6 KB
  const int tid = threadIdx.x;
  for (int e = tid; e < 6144; e += 256) {
    int b = e / 768;
    int d = e - b * 768;
    int k = d >> 6, pj = d & 63;
    int p = pj >> 2, j = pj & 3;
    s2[(k * 16 + p) * 36 + j * 8 + b] = s[e];
  }
  __syncthreads();

  const int wv = tid >> 6, l = tid & 63;
  const int g = l >> 4, p = l & 15;
  const int base = blockIdx.x * 32 + wv * 8;
  const int rA = base + g, rB = base + g + 4;
  const int cA = (rA < V_) ? rA : (V_ - 1);
  const int cB = (rB < V_) ? rB : (V_ - 1);
  const float* wpA = w + (size_t)cA * D_ + p * 4;
  const float* wpB = w + (size_t)cB * D_ + p * 4;

  float accA[8] = {}, accB[8] = {};
  float4 A0 = *(const float4*)(wpA);
  float4 B0 = *(const float4*)(wpB);
  float4 A1 = *(const float4*)(wpA + 64);
  float4 B1 = *(const float4*)(wpB + 64);
  float4 A2 = *(const float4*)(wpA + 128);
  float4 B2 = *(const float4*)(wpB + 128);
  float4 A3 = *(const float4*)(wpA + 192);
  float4 B3 = *(const float4*)(wpB + 192);

  SIM_STEP(0, A0, B0)
  SIM_STEP(1, A1, B1)
  SIM_STEP(2, A2, B2)
  SIM_STEP(3, A3, B3)
  SIM_STEP(4, A0, B0)
  SIM_STEP(5, A1, B1)
  SIM_STEP(6, A2, B2)
  SIM_STEP(7, A3, B3)
  SIM_STEP(8, A0, B0)
  SIM_STEP(9, A1, B1)
  SIM_STEP(10, A2, B2)
  SIM_STEP(11, A3, B3)

#pragma unroll
  for (int off = 1; off < 16; off <<= 1) {
#pragma unroll
    for (int b = 0; b < 8; ++b) {
      accA[b] += __shfl_xor(accA[b], off);
      accB[b] += __shfl_xor(accB[b], off);
    }
  }
  if (p == 0) {
#pragma unroll
    for (int b = 0; b < 8; ++b) {
      if (rA < V_) sim[(size_t)b * V_ + rA] = accA[b];
      if (rB < V_) sim[(size_t)b * V_ + rB] = accB[b];
    }
  }
}

// ---------------------------------------------------------------------------
// Kernel 6a: per-chunk local top-10.
// ---------------------------------------------------------------------------
__global__ __launch_bounds__(256) void topk_stage1(
    const float* __restrict__ sim, float* __restrict__ cv,
    int* __restrict__ ci) {
  __shared__ float vals[CHUNK_SZ_];
  __shared__ float bv[256];
  __shared__ int bi[256];
  const int chunk = blockIdx.x, b = blockIdx.y, tid = threadIdx.x;
  const int base = chunk * CHUNK_SZ_;
  const float* row = sim + (size_t)b * V_;
  for (int i = tid; i < CHUNK_SZ_; i += 256) {
    int v = base + i;
    vals[i] = (v < V_) ? row[v] : -INFINITY;
  }
  __syncthreads();
  for (int k = 0; k < TOPK_; ++k) {
    float best = -INFINITY;
    int besti = CHUNK_SZ_;
    for (int i = tid; i < CHUNK_SZ_; i += 256) {
      float x = vals[i];
      if (x > best) { best = x; besti = i; }
    }
    bv[tid] = best; bi[tid] = besti;
    __syncthreads();
    for (int off = 128; off > 0; off >>= 1) {
      if (tid < off) {
        float ov = bv[tid + off]; int oi = bi[tid + off];
        if (ov > bv[tid] || (ov == bv[tid] && oi < bi[tid])) {
          bv[tid] = ov; bi[tid] = oi;
        }
      }
      __syncthreads();
    }
    if (tid == 0) {
      int slot = (b * CHUNKS_ + chunk) * TOPK_ + k;
      cv[slot] = bv[0];
      ci[slot] = base + bi[0];
      if (bi[0] < CHUNK_SZ_) vals[bi[0]] = -INFINITY;
    }
    __syncthreads();
  }
}

// ---------------------------------------------------------------------------
// Kernel 6b: reduce 64 chunks x 10 candidates -> global top-10 per batch.
// ---------------------------------------------------------------------------
__global__ __launch_bounds__(256) void topk_stage2(
    const float* __restrict__ cv, const int* __restrict__ ci,
    int* __restrict__ topk) {
  const int NC = CHUNKS_ * TOPK_;  // 640
  __shared__ float vals[CHUNKS_ * TOPK_];
  __shared__ int gidx[CHUNKS_ * TOPK_];
  __shared__ float bv[256];
  __shared__ int bi[256];
  const int b = blockIdx.x, tid = threadIdx.x;
  for (int i = tid; i < NC; i += 256) {
    vals[i] = cv[(size_t)b * NC + i];
    gidx[i] = ci[(size_t)b * NC + i];
  }
  __syncthreads();
  for (int k = 0; k < TOPK_; ++k) {
    float best = -INFINITY;
    int bslot = NC;
    for (int i = tid; i < NC; i += 256) {
      float x = vals[i];
      if (x > best) { best = x; bslot = i; }
    }
    bv[tid] = best; bi[tid] = bslot;
    __syncthreads();
    for (int off = 128; off > 0; off >>= 1) {
      if (tid < off) {
        float ov = bv[tid + off]; int oi = bi[tid + off];
        if (ov > bv[tid] || (ov == bv[tid] && oi < bi[tid])) {
          bv[tid] = ov; bi[tid] = oi;
        }
      }
      __syncthreads();
    }
    if (tid == 0) {
      int slot = bi[0];
      topk[b * TOPK_ + k] = (slot < NC) ? gidx[slot] : 0;
      if (slot < NC) vals[slot] = -INFINITY;
    }
    __syncthreads();
  }
}

// ---------------------------------------------------------------------------
// Kernel 7: gather word_emd rows -> output [B, K, D]
// ---------------------------------------------------------------------------
__global__ void gather_kernel(const int* __restrict__ topk,
                              const float* __restrict__ w,
                              float* __restrict__ out) {
  const int bk = blockIdx.x;
  const int idx = topk[bk];
  const int t4 = threadIdx.x << 2;
  *(float4*)(out + (size_t)bk * D_ + t4) =
      *(const float4*)(w + (size_t)idx * D_ + t4);
}

extern "C" void kernel_launch(void* const* d_in, const int* in_sizes, int n_in,
                              void* d_out, int out_size, void* d_ws,
                              size_t ws_size, hipStream_t stream) {
  const float* prompt = (const float*)d_in[0];
  const float* enc    = (const float*)d_in[1];
  const float* wemd   = (const float*)d_in[2];
  const float* Wqkv   = (const float*)d_in[3];
  const float* Wproj  = (const float*)d_in[4];
  const float* bproj  = (const float*)d_in[5];
  float* out = (float*)d_out;

  float* ws = (float*)d_ws;
  const size_t QSZ = (size_t)B_ * H_ * L_ * HD_;  // 3,538,944
  float* Vv   = ws;                        // fp32 V
  float* c    = Vv + QSZ;                  // 96*576 = 55,296
  float* t    = c + (size_t)B_ * H_ * L_;  // 6144
  float* s    = t + (size_t)B_ * D_;       // 6144
  float* sim  = s + (size_t)B_ * D_;       // 8*50257 = 402,056
  float* cand_v = sim + (size_t)B_ * V_;   // 8*640 = 5120
  int* cand_i   = (int*)(cand_v + (size_t)B_ * CHUNKS_ * TOPK_);
  int* topk     = cand_i + (size_t)B_ * CHUNKS_ * TOPK_;
  unsigned short* Qhi = (unsigned short*)(topk + B_ * TOPK_ + 64);
  unsigned short* Qlo = Qhi + QSZ;
  unsigned short* Khi = Qlo + QSZ;
  unsigned short* Klo = Khi + QSZ;
  unsigned short* Ahi = Klo + QSZ;
  unsigned short* Alo = Ahi + (size_t)M_QKV * K_QKV;
  unsigned short* Bhi = Alo + (size_t)M_QKV * K_QKV;
  unsigned short* Blo = Bhi + (size_t)N_QKV * K_QKV;

  // zero c AND t (contiguous) — cv accumulates into t with atomics
  hipMemsetAsync(c, 0, ((size_t)B_ * H_ * L_ + (size_t)B_ * D_) * sizeof(float),
                 stream);

  const int NCONV = (M_QKV * K_QKV + N_QKV * K_QKV) / 4;  // 1,327,104
  convert_split<<<(NCONV + 255) / 256, 256, 0, stream>>>(
      prompt, enc, Wqkv, Ahi, Alo, Bhi, Blo);
  qkv_mfma<<<(M_QKV / 64) * (N_QKV / 128), 256, 0, stream>>>(
      Ahi, Alo, Bhi, Blo, Qhi, Qlo, Khi, Klo, Vv);
  attn_mfma<<<dim3(9, 96), 256, 0, stream>>>(Qhi, Qlo, Khi, Klo, c);
  cv_kernel<<<dim3(96, 4), 64, 0, stream>>>(c, Vv, t);
  proj_kernel<<<D_ / 4, 256, 0, stream>>>(t, Wproj, bproj, s);
  sim_kernel<<<(V_ + 31) / 32, 256, 0, stream>>>(s, wemd, sim);
  topk_stage1<<<dim3(CHUNKS_, B_), 256, 0, stream>>>(sim, cand_v, cand_i);
  topk_stage2<<<B_, 256, 0, stream>>>(cand_v, cand_i, topk);
  gather_kernel<<<80, 192, 0, stream>>>(topk, wemd, out);
}